// Round 7
// baseline (809.572 us; speedup 1.0000x reference)
//
#include <hip/hip_runtime.h>
#include <stdint.h>

static constexpr int NT = 26000;   // n_terms
static constexpr int NE = 120000;  // n_edges

typedef __attribute__((ext_vector_type(8))) short short8;   // 8 bf16 (MFMA A/B frag)
typedef __attribute__((ext_vector_type(4))) float f32x4;    // MFMA C/D frag

// ---------- bf16 helpers ----------
__device__ __forceinline__ float bf_lo(uint32_t u){ union{uint32_t u; float f;} a; a.u = u<<16; return a.f; }
__device__ __forceinline__ float bf_hi(uint32_t u){ union{uint32_t u; float f;} a; a.u = u & 0xffff0000u; return a.f; }
__device__ __forceinline__ uint32_t f2b(float f){ union{float f; uint32_t u;} a; a.f=f; return (a.u + 0x7fffu + ((a.u>>16)&1u))>>16; }

// Node-block tiled layout, BB=16 rows (bf16 element (row,k) -> u32 offset within block):
//   pos_u32 = (k>>4)*128 + row*8 + (k&15)/2      (block = 8*CIN u32)
// 16x16-bf16 = 512B subtiles -> wave gathers/stores are contiguous bursts.

// ---------- CSR build ----------
__global__ __launch_bounds__(256) void k_zero_deg(int* __restrict__ deg){
  int i = blockIdx.x*256 + threadIdx.x;
  if (i < NT) deg[i] = 0;
}
__global__ __launch_bounds__(256) void k_count(const int* __restrict__ ei, int* __restrict__ deg){
  int e = blockIdx.x*256 + threadIdx.x;
  if (e < NE) atomicAdd(&deg[ei[e]], 1);
}
// slots = max(4, ceil4(deg)); rp = prefix(slots); cur = rp (fill advances cur to rp+deg)
__global__ __launch_bounds__(1024) void k_scan(const int* __restrict__ deg, int* __restrict__ rp,
                                               int* __restrict__ cur){
  __shared__ int part[1024];
  const int t = threadIdx.x;
  const int CH = (NT + 1023)/1024;   // 26
  const int base = t*CH;
  int sum = 0;
  for (int i=0;i<CH;i++){
    int idx=base+i;
    if (idx<NT){ int d = deg[idx]; sum += (d<=4)?4:((d+3)&~3); }
  }
  part[t] = sum;
  __syncthreads();
  for (int off=1; off<1024; off<<=1){
    int v = (t>=off) ? part[t-off] : 0;
    __syncthreads();
    part[t] += v;
    __syncthreads();
  }
  int run = (t==0) ? 0 : part[t-1];
  for (int i=0;i<CH;i++){
    int idx = base+i;
    if (idx<NT){
      int d = deg[idx];
      int slot = (d<=4)?4:((d+3)&~3);
      rp[idx] = run; cur[idx] = run;
      run += slot;
    }
  }
  if (t==1023) rp[NT] = part[1023];
}
// init: zero the 4KB zero-page; fill cols16 (224008 u16) with NT (0x6590)
__global__ __launch_bounds__(256) void k_init(uint32_t* __restrict__ zp, uint32_t* __restrict__ cols32){
  int i = blockIdx.x*256 + threadIdx.x;
  if (i < 1024) zp[i] = 0;
  else if (i < 1024 + 112004) cols32[i-1024] = 0x65906590u;  // 26000 | 26000<<16
}
__global__ __launch_bounds__(256) void k_fill(const int* __restrict__ ei, int* __restrict__ cur,
                                              uint16_t* __restrict__ cols){
  int e = blockIdx.x*256 + threadIdx.x;
  if (e < NE){
    int r = ei[e];
    int pos = atomicAdd(&cur[r], 1);
    cols[pos] = (uint16_t)ei[NE + e];
  }
}
// pre-pack weights to bf16 [COUT][CIN] row-major, zero-padded K
__global__ __launch_bounds__(256) void k_prepw(const float* __restrict__ W1, const float* __restrict__ W2,
                                               const float* __restrict__ W3,
                                               uint16_t* __restrict__ Wt1, uint16_t* __restrict__ Wt2,
                                               uint16_t* __restrict__ Wt3){
  for (int idx = threadIdx.x; idx < 8192; idx += 256){
    if (idx < 2048){           // W1: 64 x 22 -> [64][32]
      int o = idx >> 5, k = idx & 31;
      Wt1[idx] = (uint16_t)((k < 22) ? f2b(W1[o*22 + k]) : 0);
    } else if (idx < 6144){    // W2: 64 x 64
      int j = idx - 2048;
      Wt2[j] = (uint16_t)f2b(W2[j]);
    } else {                   // W3: 32 x 64
      int j = idx - 6144;
      Wt3[j] = (uint16_t)f2b(W3[j]);
    }
  }
}

// ---------- build h0 (tiled, BB=16): [N] blocks of 16 rows x 32 k bf16 = 1KB ----------
__global__ __launch_bounds__(256) void k_build_h0(const float* __restrict__ x, const int* __restrict__ tidx,
                                                  const float* __restrict__ emb, uint32_t* __restrict__ h0){
  int n = blockIdx.x*16 + (threadIdx.x>>4);
  int b = threadIdx.x & 15;
  const float* xr = x + ((size_t)b*NT + n)*14;
  const float* er = emb + (size_t)tidx[n]*8;
  float v[32];
  #pragma unroll
  for (int i=0;i<14;i++) v[i]=xr[i];
  #pragma unroll
  for (int i=0;i<8;i++) v[14+i]=er[i];
  #pragma unroll
  for (int i=22;i<32;i++) v[i]=0.f;
  uint32_t p[16];
  #pragma unroll
  for (int u=0;u<16;u++) p[u] = f2b(v[2*u]) | (f2b(v[2*u+1])<<16);
  uint32_t* dst = h0 + (size_t)n*256;     // 8*CIN u32, CIN=32
  *reinterpret_cast<uint4*>(dst + b*8)       = make_uint4(p[0],p[1],p[2],p[3]);
  *reinterpret_cast<uint4*>(dst + b*8 + 4)   = make_uint4(p[4],p[5],p[6],p[7]);
  *reinterpret_cast<uint4*>(dst + 128 + b*8)     = make_uint4(p[8],p[9],p[10],p[11]);
  *reinterpret_cast<uint4*>(dst + 128 + b*8 + 4) = make_uint4(p[12],p[13],p[14],p[15]);
}

// ---------- gather helpers ----------
template<int STR>   // STR = u32 per node block = 8*CIN
__device__ __forceinline__ const uint32_t* nb(const uint32_t* __restrict__ hin,
                                              const uint32_t* __restrict__ zp, int c){
  return (c < NT) ? (hin + (size_t)c*STR) : zp;   // scalar select (c wave-uniform)
}
template<int KS>
__device__ __forceinline__ void gloadv(uint4 (&v)[KS], const uint32_t* __restrict__ p,
                                       const uint32_t (&off)[KS]){
  #pragma unroll
  for (int ks=0; ks<KS; ks++) v[ks] = *reinterpret_cast<const uint4*>(p + off[ks]);
}
template<int KS>
__device__ __forceinline__ void accum(float (&acc)[KS][8], const uint4 (&v)[KS]){
  #pragma unroll
  for (int ks=0;ks<KS;ks++){
    acc[ks][0]+=bf_lo(v[ks].x); acc[ks][1]+=bf_hi(v[ks].x);
    acc[ks][2]+=bf_lo(v[ks].y); acc[ks][3]+=bf_hi(v[ks].y);
    acc[ks][4]+=bf_lo(v[ks].z); acc[ks][5]+=bf_hi(v[ks].z);
    acc[ks][6]+=bf_lo(v[ks].w); acc[ks][7]+=bf_hi(v[ks].w);
  }
}

// ---------- gather+GEMM layer (L1,L2): 1 wave per node (16 batch rows); no LDS/barriers;
// branch-free depth-4 edge pipeline; h_out = relu((own + di*sum(nbr)) @ W^T + b), tiled store.
template<int CIN, int COUT>
__global__ __launch_bounds__(256, 8) void k_layer(
    const uint32_t* __restrict__ hin,   // [NT] tiled blocks, CIN wide
    uint32_t* __restrict__ hout,        // [NT] tiled blocks, COUT wide
    const int* __restrict__ rp, const int* __restrict__ cur,
    const uint16_t* __restrict__ cols, const uint32_t* __restrict__ zp,
    const uint16_t* __restrict__ Wt,    // [COUT][CIN] bf16 row-major
    const float* __restrict__ bias)
{
  constexpr int KS  = CIN/32;
  constexpr int OT  = COUT/16;
  constexpr int STR = 8*CIN;

  const int t    = threadIdx.x;
  const int lane = t & 63;
  const int w    = t >> 6;
  const int l15  = lane & 15;
  const int lg   = lane >> 4;
  const int node = blockIdx.x*4 + w;

  uint32_t off[KS];
  #pragma unroll
  for (int ks=0;ks<KS;ks++)
    off[ks] = (uint32_t)((ks*2 + (lg>>1))*128 + l15*8 + (lg&1)*4);

  const int e0 = __builtin_amdgcn_readfirstlane(rp[node]);
  const int e1 = __builtin_amdgcn_readfirstlane(rp[node+1]);
  const int dg = __builtin_amdgcn_readfirstlane(cur[node]) - e0;

  uint2 cc0 = *reinterpret_cast<const uint2*>(cols + e0);
  int q0 = __builtin_amdgcn_readfirstlane(cc0.x);
  int q1 = __builtin_amdgcn_readfirstlane(cc0.y);
  uint4 v0[KS], v1[KS], v2[KS], v3[KS], own[KS];
  gloadv<KS>(v0, nb<STR>(hin, zp, q0 & 0xffff), off);
  gloadv<KS>(v1, nb<STR>(hin, zp, (q0 >> 16) & 0xffff), off);
  gloadv<KS>(v2, nb<STR>(hin, zp, q1 & 0xffff), off);
  gloadv<KS>(v3, nb<STR>(hin, zp, (q1 >> 16) & 0xffff), off);
  gloadv<KS>(own, hin + (size_t)node*STR, off);
  uint2 ccA = *reinterpret_cast<const uint2*>(cols + e0 + 4);

  const float degf = (float)(dg > 1 ? dg : 1);
  float acc[KS][8];
  #pragma unroll
  for (int ks=0;ks<KS;ks++){
    acc[ks][0]=bf_lo(own[ks].x)*degf; acc[ks][1]=bf_hi(own[ks].x)*degf;
    acc[ks][2]=bf_lo(own[ks].y)*degf; acc[ks][3]=bf_hi(own[ks].y)*degf;
    acc[ks][4]=bf_lo(own[ks].z)*degf; acc[ks][5]=bf_hi(own[ks].z)*degf;
    acc[ks][6]=bf_lo(own[ks].w)*degf; acc[ks][7]=bf_hi(own[ks].w)*degf;
  }

  for (int e = e0; e < e1; e += 4){
    uint2 ccN = *reinterpret_cast<const uint2*>(cols + e + 8);   // 8 sentinels at array end
    int p0 = __builtin_amdgcn_readfirstlane(ccA.x);
    int p1 = __builtin_amdgcn_readfirstlane(ccA.y);
    int n0 = (e+4 < e1) ? (p0 & 0xffff)         : NT;
    int n1 = (e+5 < e1) ? ((p0 >> 16) & 0xffff) : NT;
    int n2 = (e+6 < e1) ? (p1 & 0xffff)         : NT;
    int n3 = (e+7 < e1) ? ((p1 >> 16) & 0xffff) : NT;
    accum<KS>(acc, v0); gloadv<KS>(v0, nb<STR>(hin, zp, n0), off);
    accum<KS>(acc, v1); gloadv<KS>(v1, nb<STR>(hin, zp, n1), off);
    accum<KS>(acc, v2); gloadv<KS>(v2, nb<STR>(hin, zp, n2), off);
    accum<KS>(acc, v3); gloadv<KS>(v3, nb<STR>(hin, zp, n3), off);
    ccA = ccN;
  }

  const float di = 1.0f / degf;
  short8 bfrag[KS];
  #pragma unroll
  for (int ks=0;ks<KS;ks++){
    short8 bf;
    #pragma unroll
    for (int j=0;j<8;j++) bf[j] = (short)f2b(acc[ks][j]*di);
    bfrag[ks]=bf;
  }

  #pragma unroll
  for (int ot=0;ot<OT;ot++){
    const int o0 = ot*16;
    short8 af[KS];
    #pragma unroll
    for (int ks=0;ks<KS;ks++)
      af[ks] = *reinterpret_cast<const short8*>(Wt + (o0 + l15)*CIN + ks*32 + lg*8);
    f32x4 d = *reinterpret_cast<const f32x4*>(bias + o0 + lg*4);   // bias folded into C
    #pragma unroll
    for (int ks=0;ks<KS;ks++)
      d = __builtin_amdgcn_mfma_f32_16x16x32_bf16(af[ks], bfrag[ks], d, 0,0,0);
    float a0=fmaxf(d[0],0.f), a1=fmaxf(d[1],0.f), a2=fmaxf(d[2],0.f), a3=fmaxf(d[3],0.f);
    uint2 p; p.x = f2b(a0) | (f2b(a1)<<16); p.y = f2b(a2) | (f2b(a3)<<16);
    *reinterpret_cast<uint2*>(hout + (size_t)node*(8*COUT) + ot*128 + l15*8 + lg*2) = p;
  }
}

// ---------- streaming GEMM3: Y3 = h2 @ W3^T (no bias, no relu), 64 -> 32 wide ----------
__global__ __launch_bounds__(256, 8) void k_gemm3(
    const uint32_t* __restrict__ hin,   // [NT] tiled 64-wide (2KB)
    uint32_t* __restrict__ hout,        // [NT] tiled 32-wide (1KB)
    const uint16_t* __restrict__ Wt)    // [32][64] bf16
{
  const int t    = threadIdx.x;
  const int lane = t & 63;
  const int w    = t >> 6;
  const int l15  = lane & 15;
  const int lg   = lane >> 4;
  const int node = blockIdx.x*4 + w;

  const uint32_t* p = hin + (size_t)node*512;
  short8 bfrag[2];
  #pragma unroll
  for (int ks=0;ks<2;ks++)
    bfrag[ks] = *reinterpret_cast<const short8*>(p + (ks*2 + (lg>>1))*128 + l15*8 + (lg&1)*4);

  #pragma unroll
  for (int ot=0;ot<2;ot++){
    const int o0 = ot*16;
    short8 af[2];
    #pragma unroll
    for (int ks=0;ks<2;ks++)
      af[ks] = *reinterpret_cast<const short8*>(Wt + (o0 + l15)*64 + ks*32 + lg*8);
    f32x4 d = {0.f,0.f,0.f,0.f};
    #pragma unroll
    for (int ks=0;ks<2;ks++)
      d = __builtin_amdgcn_mfma_f32_16x16x32_bf16(af[ks], bfrag[ks], d, 0,0,0);
    uint2 q; q.x = f2b(d[0]) | (f2b(d[1])<<16); q.y = f2b(d[2]) | (f2b(d[3])<<16);
    *reinterpret_cast<uint2*>(hout + (size_t)node*256 + ot*128 + l15*8 + lg*2) = q;
  }
}

// ---------- final: aggregate Y3 (32-wide) + bias + relu + head dot + sigmoid ----------
__global__ __launch_bounds__(256, 8) void k_fin(
    const uint32_t* __restrict__ hin,   // [NT] tiled 32-wide Y3 (1KB)
    const int* __restrict__ rp, const int* __restrict__ cur,
    const uint16_t* __restrict__ cols, const uint32_t* __restrict__ zp,
    const float* __restrict__ b3, const float* __restrict__ Wo, const float* __restrict__ bo,
    float* __restrict__ tmp)            // [NT][16] f32
{
  constexpr int STR = 256;
  const int t    = threadIdx.x;
  const int lane = t & 63;
  const int w    = t >> 6;
  const int l15  = lane & 15;
  const int lg   = lane >> 4;
  const int node = blockIdx.x*4 + w;

  uint32_t off[1];
  off[0] = (uint32_t)((lg>>1)*128 + l15*8 + (lg&1)*4);

  const int e0 = __builtin_amdgcn_readfirstlane(rp[node]);
  const int e1 = __builtin_amdgcn_readfirstlane(rp[node+1]);
  const int dg = __builtin_amdgcn_readfirstlane(cur[node]) - e0;

  uint2 cc0 = *reinterpret_cast<const uint2*>(cols + e0);
  int q0 = __builtin_amdgcn_readfirstlane(cc0.x);
  int q1 = __builtin_amdgcn_readfirstlane(cc0.y);
  uint4 v0[1], v1[1], v2[1], v3[1], own[1];
  gloadv<1>(v0, nb<STR>(hin, zp, q0 & 0xffff), off);
  gloadv<1>(v1, nb<STR>(hin, zp, (q0 >> 16) & 0xffff), off);
  gloadv<1>(v2, nb<STR>(hin, zp, q1 & 0xffff), off);
  gloadv<1>(v3, nb<STR>(hin, zp, (q1 >> 16) & 0xffff), off);
  gloadv<1>(own, hin + (size_t)node*STR, off);
  uint2 ccA = *reinterpret_cast<const uint2*>(cols + e0 + 4);

  const float degf = (float)(dg > 1 ? dg : 1);
  float acc[1][8];
  acc[0][0]=bf_lo(own[0].x)*degf; acc[0][1]=bf_hi(own[0].x)*degf;
  acc[0][2]=bf_lo(own[0].y)*degf; acc[0][3]=bf_hi(own[0].y)*degf;
  acc[0][4]=bf_lo(own[0].z)*degf; acc[0][5]=bf_hi(own[0].z)*degf;
  acc[0][6]=bf_lo(own[0].w)*degf; acc[0][7]=bf_hi(own[0].w)*degf;

  for (int e = e0; e < e1; e += 4){
    uint2 ccN = *reinterpret_cast<const uint2*>(cols + e + 8);
    int p0 = __builtin_amdgcn_readfirstlane(ccA.x);
    int p1 = __builtin_amdgcn_readfirstlane(ccA.y);
    int n0 = (e+4 < e1) ? (p0 & 0xffff)         : NT;
    int n1 = (e+5 < e1) ? ((p0 >> 16) & 0xffff) : NT;
    int n2 = (e+6 < e1) ? (p1 & 0xffff)         : NT;
    int n3 = (e+7 < e1) ? ((p1 >> 16) & 0xffff) : NT;
    accum<1>(acc, v0); gloadv<1>(v0, nb<STR>(hin, zp, n0), off);
    accum<1>(acc, v1); gloadv<1>(v1, nb<STR>(hin, zp, n1), off);
    accum<1>(acc, v2); gloadv<1>(v2, nb<STR>(hin, zp, n2), off);
    accum<1>(acc, v3); gloadv<1>(v3, nb<STR>(hin, zp, n3), off);
    ccA = ccN;
  }

  // s3 = acc*di + b3; h3 = relu(s3); z = sum_k h3*Wo
  const float di = 1.0f / degf;
  const int k0 = lg*8;
  f32x4 bA = *reinterpret_cast<const f32x4*>(b3 + k0);
  f32x4 bB = *reinterpret_cast<const f32x4*>(b3 + k0 + 4);
  f32x4 wA = *reinterpret_cast<const f32x4*>(Wo + k0);
  f32x4 wB = *reinterpret_cast<const f32x4*>(Wo + k0 + 4);
  float z = 0.f;
  #pragma unroll
  for (int j=0;j<4;j++){
    z += fmaxf(acc[0][j]  *di + bA[j], 0.f) * wA[j];
    z += fmaxf(acc[0][4+j]*di + bB[j], 0.f) * wB[j];
  }
  z += __shfl_xor(z, 16, 64);
  z += __shfl_xor(z, 32, 64);
  if (lg == 0){
    float sg = 1.f/(1.f + expf(-(z + bo[0])));
    tmp[(size_t)node*16 + l15] = sg;
  }
}

// ---------- transpose tmp [NT][16] -> out [16][NT] (coalesced writes) ----------
__global__ __launch_bounds__(256) void k_tr(const float* __restrict__ tmp, float* __restrict__ out){
  int n = blockIdx.x*256 + threadIdx.x;
  if (n < NT){
    f32x4 r[4];
    #pragma unroll
    for (int q=0;q<4;q++) r[q] = *reinterpret_cast<const f32x4*>(tmp + (size_t)n*16 + q*4);
    #pragma unroll
    for (int q=0;q<4;q++)
      #pragma unroll
      for (int j=0;j<4;j++)
        out[(size_t)(q*4+j)*NT + n] = r[q][j];
  }
}

// ---------- workspace layout (bytes); total ~135.6 MB ----------
static constexpr size_t OFF_P    = 0;                         // 26,624,000  (32-wide blocks)
static constexpr size_t OFF_Q    = 26624000;                  // 53,248,000  (64-wide)
static constexpr size_t OFF_R    = 79872000;                  // 53,248,000  (64-wide)
static constexpr size_t OFF_TMP  = 133120000;                 // 1,664,000   (NT*16 f32)
static constexpr size_t OFF_ZP   = 134784000;                 // 4 KB zero page
static constexpr size_t OFF_WT1  = OFF_ZP  + 4096;
static constexpr size_t OFF_WT2  = OFF_WT1 + 4096;
static constexpr size_t OFF_WT3  = OFF_WT2 + 8192;
static constexpr size_t OFF_DEG  = OFF_WT3 + 4096;
static constexpr size_t OFF_RP   = OFF_DEG + 104000;
static constexpr size_t OFF_CUR  = OFF_RP  + 104016;
static constexpr size_t OFF_COLS = OFF_CUR + 104000;
static constexpr size_t WS_NEED  = OFF_COLS + 448016;         // cols: 224008 u16 (incl sentinels)

extern "C" void kernel_launch(void* const* d_in, const int* in_sizes, int n_in,
                              void* d_out, int out_size, void* d_ws, size_t ws_size,
                              hipStream_t stream)
{
  const float* x    = (const float*)d_in[0];
  const int*   ei   = (const int*)  d_in[1];
  const int*   tidx = (const int*)  d_in[2];
  const float* emb  = (const float*)d_in[3];
  const float* W1   = (const float*)d_in[4];
  const float* b1   = (const float*)d_in[5];
  const float* W2   = (const float*)d_in[6];
  const float* b2   = (const float*)d_in[7];
  const float* W3   = (const float*)d_in[8];
  const float* b3   = (const float*)d_in[9];
  const float* Wo   = (const float*)d_in[10];
  const float* bo   = (const float*)d_in[11];
  float* out = (float*)d_out;

  if (ws_size < WS_NEED) return;

  char* ws = (char*)d_ws;
  uint32_t* P    = (uint32_t*)(ws + OFF_P);
  uint32_t* Q    = (uint32_t*)(ws + OFF_Q);
  uint32_t* R    = (uint32_t*)(ws + OFF_R);
  float*    tmpf = (float*)   (ws + OFF_TMP);
  uint32_t* zp   = (uint32_t*)(ws + OFF_ZP);
  uint16_t* Wt1  = (uint16_t*)(ws + OFF_WT1);
  uint16_t* Wt2  = (uint16_t*)(ws + OFF_WT2);
  uint16_t* Wt3  = (uint16_t*)(ws + OFF_WT3);
  int*      deg  = (int*)     (ws + OFF_DEG);
  int*      rp   = (int*)     (ws + OFF_RP);
  int*      cur  = (int*)     (ws + OFF_CUR);
  uint16_t* cols = (uint16_t*)(ws + OFF_COLS);

  k_zero_deg<<<(NT+255)/256, 256, 0, stream>>>(deg);
  k_count   <<<(NE+255)/256, 256, 0, stream>>>(ei, deg);
  k_scan    <<<1, 1024, 0, stream>>>(deg, rp, cur);
  k_init    <<<442, 256, 0, stream>>>(zp, (uint32_t*)cols);
  k_fill    <<<(NE+255)/256, 256, 0, stream>>>(ei, cur, cols);
  k_prepw   <<<1, 256, 0, stream>>>(W1, W2, W3, Wt1, Wt2, Wt3);

  for (int ch = 0; ch < 4; ch++){
    k_build_h0<<<NT/16, 256, 0, stream>>>(x + (size_t)ch*16*NT*14, tidx, emb, P);
    k_layer<32,64><<<NT/4, 256, 0, stream>>>(P, Q, rp, cur, cols, zp, Wt1, b1);
    k_layer<64,64><<<NT/4, 256, 0, stream>>>(Q, R, rp, cur, cols, zp, Wt2, b2);
    k_gemm3<<<NT/4, 256, 0, stream>>>(R, P, Wt3);
    k_fin  <<<NT/4, 256, 0, stream>>>(P, rp, cur, cols, zp, b3, Wo, bo, tmpf);
    k_tr   <<<(NT+255)/256, 256, 0, stream>>>(tmpf, out + (size_t)ch*16*NT);
  }
}

// Round 8
// 560.379 us; speedup vs baseline: 1.4447x; 1.4447x over previous
//
#include <hip/hip_runtime.h>
#include <stdint.h>

static constexpr int NT = 26000;   // n_terms
static constexpr int NE = 120000;  // n_edges

typedef __attribute__((ext_vector_type(8))) short short8;   // 8 bf16 (MFMA A/B frag)
typedef __attribute__((ext_vector_type(4))) float f32x4;    // MFMA C/D frag
typedef __attribute__((ext_vector_type(2))) unsigned int u32x2;

// ---------- bf16 helpers ----------
__device__ __forceinline__ float bf_lo(uint32_t u){ union{uint32_t u; float f;} a; a.u = u<<16; return a.f; }
__device__ __forceinline__ float bf_hi(uint32_t u){ union{uint32_t u; float f;} a; a.u = u & 0xffff0000u; return a.f; }
__device__ __forceinline__ uint32_t f2b(float f){ union{float f; uint32_t u;} a; a.f=f; return (a.u + 0x7fffu + ((a.u>>16)&1u))>>16; }

__device__ __forceinline__ void nts2(uint32_t* p, uint32_t a, uint32_t b){
  u32x2 v; v.x = a; v.y = b;
  __builtin_nontemporal_store(v, reinterpret_cast<u32x2*>(p));
}

// Node-block tiled layout, BB=32 rows (bf16 (brow,k) -> u32 offset within block):
//   pos_u32 = (brow>>4)*(C*8) + (k>>4)*128 + (brow&15)*8 + (k&15)/2     (block = 16*C u32)

// ---------- CSR build ----------
__global__ __launch_bounds__(256) void k_zero_deg(int* __restrict__ deg){
  int i = blockIdx.x*256 + threadIdx.x;
  if (i < NT) deg[i] = 0;
}
__global__ __launch_bounds__(256) void k_count(const int* __restrict__ ei, int* __restrict__ deg){
  int e = blockIdx.x*256 + threadIdx.x;
  if (e < NE) atomicAdd(&deg[ei[e]], 1);
}
// slots = max(4, ceil4(deg)); rp = prefix(slots); cur = rp (fill advances cur to rp+deg)
__global__ __launch_bounds__(1024) void k_scan(const int* __restrict__ deg, int* __restrict__ rp,
                                               int* __restrict__ cur){
  __shared__ int part[1024];
  const int t = threadIdx.x;
  const int CH = (NT + 1023)/1024;   // 26
  const int base = t*CH;
  int sum = 0;
  for (int i=0;i<CH;i++){
    int idx=base+i;
    if (idx<NT){ int d = deg[idx]; sum += (d<=4)?4:((d+3)&~3); }
  }
  part[t] = sum;
  __syncthreads();
  for (int off=1; off<1024; off<<=1){
    int v = (t>=off) ? part[t-off] : 0;
    __syncthreads();
    part[t] += v;
    __syncthreads();
  }
  int run = (t==0) ? 0 : part[t-1];
  for (int i=0;i<CH;i++){
    int idx = base+i;
    if (idx<NT){
      int d = deg[idx];
      int slot = (d<=4)?4:((d+3)&~3);
      rp[idx] = run; cur[idx] = run;
      run += slot;
    }
  }
  if (t==1023) rp[NT] = part[1023];
}
// init: zero the 4KB zero-page; fill cols16 (224008 u16) with NT (0x6590)
__global__ __launch_bounds__(256) void k_init(uint32_t* __restrict__ zp, uint32_t* __restrict__ cols32){
  int i = blockIdx.x*256 + threadIdx.x;
  if (i < 1024) zp[i] = 0;
  else if (i < 1024 + 112004) cols32[i-1024] = 0x65906590u;
}
__global__ __launch_bounds__(256) void k_fill(const int* __restrict__ ei, int* __restrict__ cur,
                                              uint16_t* __restrict__ cols){
  int e = blockIdx.x*256 + threadIdx.x;
  if (e < NE){
    int r = ei[e];
    int pos = atomicAdd(&cur[r], 1);
    cols[pos] = (uint16_t)ei[NE + e];
  }
}
// pre-pack weights to bf16 [COUT][CIN] row-major, zero-padded K
__global__ __launch_bounds__(256) void k_prepw(const float* __restrict__ W1, const float* __restrict__ W2,
                                               const float* __restrict__ W3,
                                               uint16_t* __restrict__ Wt1, uint16_t* __restrict__ Wt2,
                                               uint16_t* __restrict__ Wt3){
  for (int idx = threadIdx.x; idx < 8192; idx += 256){
    if (idx < 2048){           // W1: 64 x 22 -> [64][32]
      int o = idx >> 5, k = idx & 31;
      Wt1[idx] = (uint16_t)((k < 22) ? f2b(W1[o*22 + k]) : 0);
    } else if (idx < 6144){    // W2: 64 x 64
      int j = idx - 2048;
      Wt2[j] = (uint16_t)f2b(W2[j]);
    } else {                   // W3: 32 x 64
      int j = idx - 6144;
      Wt3[j] = (uint16_t)f2b(W3[j]);
    }
  }
}

// ---------- build h0 (tiled, BB=32): [N] blocks of 32 rows x 32 k bf16 = 2KB ----------
// lanes 0-15 take consecutive n (coalesced 896B x-read windows); each thread does rows b0,b0+16
__global__ __launch_bounds__(256) void k_build_h0(const float* __restrict__ x, const int* __restrict__ tidx,
                                                  const float* __restrict__ emb, uint32_t* __restrict__ h0){
  const int n  = blockIdx.x*16 + (threadIdx.x & 15);
  const int b0 = threadIdx.x >> 4;           // 0..15
  const float* er = emb + (size_t)tidx[n]*8;
  float ev[8];
  #pragma unroll
  for (int i=0;i<8;i++) ev[i]=er[i];
  uint32_t* dst = h0 + (size_t)n*512;        // 16*CIN u32, CIN=32

  #pragma unroll
  for (int h=0; h<2; h++){
    const int b = b0 + h*16;
    const float* xr = x + ((size_t)b*NT + n)*14;
    float v[32];
    #pragma unroll
    for (int i=0;i<14;i++) v[i]=xr[i];
    #pragma unroll
    for (int i=0;i<8;i++) v[14+i]=ev[i];
    #pragma unroll
    for (int i=22;i<32;i++) v[i]=0.f;
    uint32_t p[16];
    #pragma unroll
    for (int u=0;u<16;u++) p[u] = f2b(v[2*u]) | (f2b(v[2*u+1])<<16);
    const int base = (b>>4)*256 + (b&15)*8;
    *reinterpret_cast<uint4*>(dst + base)       = make_uint4(p[0],p[1],p[2],p[3]);
    *reinterpret_cast<uint4*>(dst + base + 4)   = make_uint4(p[4],p[5],p[6],p[7]);
    *reinterpret_cast<uint4*>(dst + base + 128)     = make_uint4(p[8],p[9],p[10],p[11]);
    *reinterpret_cast<uint4*>(dst + base + 132) = make_uint4(p[12],p[13],p[14],p[15]);
  }
}

// ---------- gather helpers ----------
template<int STR>   // STR = u32 per node block = 16*C
__device__ __forceinline__ const uint32_t* nbp(const uint32_t* __restrict__ hin,
                                               const uint32_t* __restrict__ zp, int c){
  return (c < NT) ? (hin + (size_t)c*STR) : zp;   // scalar select (c wave-uniform)
}
template<int KS>
__device__ __forceinline__ void gloadv(uint4 (&v)[KS], const uint32_t* __restrict__ p,
                                       const uint32_t (&off)[KS]){
  #pragma unroll
  for (int ks=0; ks<KS; ks++) v[ks] = *reinterpret_cast<const uint4*>(p + off[ks]);
}
template<int KS>
__device__ __forceinline__ void accum(float (&acc)[KS][8], const uint4 (&v)[KS]){
  #pragma unroll
  for (int ks=0;ks<KS;ks++){
    acc[ks][0]+=bf_lo(v[ks].x); acc[ks][1]+=bf_hi(v[ks].x);
    acc[ks][2]+=bf_lo(v[ks].y); acc[ks][3]+=bf_hi(v[ks].y);
    acc[ks][4]+=bf_lo(v[ks].z); acc[ks][5]+=bf_hi(v[ks].z);
    acc[ks][6]+=bf_lo(v[ks].w); acc[ks][7]+=bf_hi(v[ks].w);
  }
}

// core aggregation: acc = own*deg + sum(neighbors); returns 1/deg
template<int KS, int STR>
__device__ __forceinline__ float aggregate(float (&acc)[KS][8],
    const uint32_t* __restrict__ hin, const uint32_t* __restrict__ zp,
    const int* __restrict__ rp, const int* __restrict__ cur,
    const uint16_t* __restrict__ cols, int node, const uint32_t (&off)[KS])
{
  const int e0 = __builtin_amdgcn_readfirstlane(rp[node]);
  const int e1 = __builtin_amdgcn_readfirstlane(rp[node+1]);
  const int dg = __builtin_amdgcn_readfirstlane(cur[node]) - e0;

  uint2 cc0 = *reinterpret_cast<const uint2*>(cols + e0);
  int q0 = __builtin_amdgcn_readfirstlane(cc0.x);
  int q1 = __builtin_amdgcn_readfirstlane(cc0.y);
  uint4 v0[KS], v1[KS], v2[KS], v3[KS], own[KS];
  gloadv<KS>(v0, nbp<STR>(hin, zp, q0 & 0xffff), off);
  gloadv<KS>(v1, nbp<STR>(hin, zp, (q0 >> 16) & 0xffff), off);
  gloadv<KS>(v2, nbp<STR>(hin, zp, q1 & 0xffff), off);
  gloadv<KS>(v3, nbp<STR>(hin, zp, (q1 >> 16) & 0xffff), off);
  gloadv<KS>(own, hin + (size_t)node*STR, off);
  uint2 ccA = *reinterpret_cast<const uint2*>(cols + e0 + 4);

  const float degf = (float)(dg > 1 ? dg : 1);
  #pragma unroll
  for (int ks=0;ks<KS;ks++){
    acc[ks][0]=bf_lo(own[ks].x)*degf; acc[ks][1]=bf_hi(own[ks].x)*degf;
    acc[ks][2]=bf_lo(own[ks].y)*degf; acc[ks][3]=bf_hi(own[ks].y)*degf;
    acc[ks][4]=bf_lo(own[ks].z)*degf; acc[ks][5]=bf_hi(own[ks].z)*degf;
    acc[ks][6]=bf_lo(own[ks].w)*degf; acc[ks][7]=bf_hi(own[ks].w)*degf;
  }

  for (int e = e0; e < e1; e += 4){
    uint2 ccN = *reinterpret_cast<const uint2*>(cols + e + 8);   // 8 sentinels at end
    int p0 = __builtin_amdgcn_readfirstlane(ccA.x);
    int p1 = __builtin_amdgcn_readfirstlane(ccA.y);
    int n0 = (e+4 < e1) ? (p0 & 0xffff)         : NT;
    int n1 = (e+5 < e1) ? ((p0 >> 16) & 0xffff) : NT;
    int n2 = (e+6 < e1) ? (p1 & 0xffff)         : NT;
    int n3 = (e+7 < e1) ? ((p1 >> 16) & 0xffff) : NT;
    accum<KS>(acc, v0); gloadv<KS>(v0, nbp<STR>(hin, zp, n0), off);
    accum<KS>(acc, v1); gloadv<KS>(v1, nbp<STR>(hin, zp, n1), off);
    accum<KS>(acc, v2); gloadv<KS>(v2, nbp<STR>(hin, zp, n2), off);
    accum<KS>(acc, v3); gloadv<KS>(v3, nbp<STR>(hin, zp, n3), off);
    ccA = ccN;
  }
  return 1.0f / degf;
}

// ---------- L1: gather(P 32-wide) -> relu GEMM -> Q (64-wide), 2 waves/node ----------
__global__ __launch_bounds__(256, 8) void k_layer1(
    const uint32_t* __restrict__ hin, uint32_t* __restrict__ hout,
    const int* __restrict__ rp, const int* __restrict__ cur,
    const uint16_t* __restrict__ cols, const uint32_t* __restrict__ zp,
    const uint16_t* __restrict__ Wt, const float* __restrict__ bias)
{
  constexpr int CIN=32, COUT=64, KS=1, OT=4, STR=16*CIN;
  const int t=threadIdx.x, lane=t&63, w=t>>6, l15=lane&15, lg=lane>>4;
  const int rt = w & 1;
  const int node = blockIdx.x*2 + (w>>1);

  uint32_t off[KS];
  off[0] = (uint32_t)(rt*(CIN*8) + (lg>>1)*128 + l15*8 + (lg&1)*4);

  float acc[KS][8];
  const float di = aggregate<KS,STR>(acc, hin, zp, rp, cur, cols, node, off);

  short8 bfrag[KS];
  {
    short8 bf;
    #pragma unroll
    for (int j=0;j<8;j++) bf[j] = (short)f2b(acc[0][j]*di);
    bfrag[0]=bf;
  }

  #pragma unroll
  for (int ot=0;ot<OT;ot++){
    const int o0 = ot*16;
    short8 af = *reinterpret_cast<const short8*>(Wt + (o0 + l15)*CIN + lg*8);
    f32x4 d = *reinterpret_cast<const f32x4*>(bias + o0 + lg*4);
    d = __builtin_amdgcn_mfma_f32_16x16x32_bf16(af, bfrag[0], d, 0,0,0);
    float a0=fmaxf(d[0],0.f), a1=fmaxf(d[1],0.f), a2=fmaxf(d[2],0.f), a3=fmaxf(d[3],0.f);
    nts2(hout + (size_t)node*(16*COUT) + rt*(COUT*8) + ot*128 + l15*8 + lg*2,
         f2b(a0) | (f2b(a1)<<16), f2b(a2) | (f2b(a3)<<16));
  }
}

// ---------- L2+G3 fused: gather(Q 64-wide) -> relu GEMM(W2) -> in-wave LDS transpose
// -> GEMM(W3, no bias/relu) -> Y3 (32-wide). 2 waves/node. ----------
__global__ __launch_bounds__(256, 6) void k_l2g3(
    const uint32_t* __restrict__ hin, uint32_t* __restrict__ hout,
    const int* __restrict__ rp, const int* __restrict__ cur,
    const uint16_t* __restrict__ cols, const uint32_t* __restrict__ zp,
    const uint16_t* __restrict__ Wt2, const float* __restrict__ bias,
    const uint16_t* __restrict__ Wt3)
{
  constexpr int CIN=64, COUT=64, KS=2, OT=4, STR=16*CIN;
  __shared__ uint32_t lt[4*512];            // per-wave 512 u32 (16 rows x 64 ch bf16, tiled)

  const int t=threadIdx.x, lane=t&63, w=t>>6, l15=lane&15, lg=lane>>4;
  const int rt = w & 1;
  const int node = blockIdx.x*2 + (w>>1);

  uint32_t off[KS];
  #pragma unroll
  for (int ks=0;ks<KS;ks++)
    off[ks] = (uint32_t)(rt*(CIN*8) + (ks*2+(lg>>1))*128 + l15*8 + (lg&1)*4);

  float acc[KS][8];
  const float di = aggregate<KS,STR>(acc, hin, zp, rp, cur, cols, node, off);

  short8 bfrag[KS];
  #pragma unroll
  for (int ks=0;ks<KS;ks++){
    short8 bf;
    #pragma unroll
    for (int j=0;j<8;j++) bf[j] = (short)f2b(acc[ks][j]*di);
    bfrag[ks]=bf;
  }

  // GEMM1: h2 = relu(W2 * s^T + b2); lane holds (o=ot*16+lg*4+j, row=l15); stash to LDS tiled
  uint32_t* L = lt + w*512;
  #pragma unroll
  for (int ot=0;ot<OT;ot++){
    const int o0 = ot*16;
    short8 af0 = *reinterpret_cast<const short8*>(Wt2 + (o0 + l15)*CIN + lg*8);
    short8 af1 = *reinterpret_cast<const short8*>(Wt2 + (o0 + l15)*CIN + 32 + lg*8);
    f32x4 d = *reinterpret_cast<const f32x4*>(bias + o0 + lg*4);
    d = __builtin_amdgcn_mfma_f32_16x16x32_bf16(af0, bfrag[0], d, 0,0,0);
    d = __builtin_amdgcn_mfma_f32_16x16x32_bf16(af1, bfrag[1], d, 0,0,0);
    float a0=fmaxf(d[0],0.f), a1=fmaxf(d[1],0.f), a2=fmaxf(d[2],0.f), a3=fmaxf(d[3],0.f);
    // LDS tiled write: row=l15, k=o0+lg*4 -> (k>>4)*128 + row*8 + (k&15)/2
    *reinterpret_cast<uint2*>(L + ot*128 + l15*8 + lg*2) =
        make_uint2(f2b(a0) | (f2b(a1)<<16), f2b(a2) | (f2b(a3)<<16));
  }

  // read back as k-consecutive B-frags (same wave -> lgkmcnt ordering only)
  short8 b3f[2];
  #pragma unroll
  for (int ks=0;ks<2;ks++)
    b3f[ks] = *reinterpret_cast<const short8*>(L + (ks*2+(lg>>1))*128 + l15*8 + (lg&1)*4);

  // GEMM2: Y3 = W3 * h2^T (32 out ch); store tiled 32-wide
  #pragma unroll
  for (int ot=0;ot<2;ot++){
    const int o0 = ot*16;
    short8 af0 = *reinterpret_cast<const short8*>(Wt3 + (o0 + l15)*64 + lg*8);
    short8 af1 = *reinterpret_cast<const short8*>(Wt3 + (o0 + l15)*64 + 32 + lg*8);
    f32x4 d = {0.f,0.f,0.f,0.f};
    d = __builtin_amdgcn_mfma_f32_16x16x32_bf16(af0, b3f[0], d, 0,0,0);
    d = __builtin_amdgcn_mfma_f32_16x16x32_bf16(af1, b3f[1], d, 0,0,0);
    nts2(hout + (size_t)node*512 + rt*256 + ot*128 + l15*8 + lg*2,
         f2b(d[0]) | (f2b(d[1])<<16), f2b(d[2]) | (f2b(d[3])<<16));
  }
}

// ---------- final: aggregate Y3 (32-wide) + b3 + relu + head dot + sigmoid ----------
__global__ __launch_bounds__(256, 8) void k_fin(
    const uint32_t* __restrict__ hin,
    const int* __restrict__ rp, const int* __restrict__ cur,
    const uint16_t* __restrict__ cols, const uint32_t* __restrict__ zp,
    const float* __restrict__ b3, const float* __restrict__ Wo, const float* __restrict__ bo,
    float* __restrict__ tmp)            // [NT][32] f32
{
  constexpr int KS=1, STR=512;
  const int t=threadIdx.x, lane=t&63, w=t>>6, l15=lane&15, lg=lane>>4;
  const int rt = w & 1;
  const int node = blockIdx.x*2 + (w>>1);

  uint32_t off[KS];
  off[0] = (uint32_t)(rt*256 + (lg>>1)*128 + l15*8 + (lg&1)*4);

  float acc[KS][8];
  const float di = aggregate<KS,STR>(acc, hin, zp, rp, cur, cols, node, off);

  const int k0 = lg*8;
  f32x4 bA = *reinterpret_cast<const f32x4*>(b3 + k0);
  f32x4 bB = *reinterpret_cast<const f32x4*>(b3 + k0 + 4);
  f32x4 wA = *reinterpret_cast<const f32x4*>(Wo + k0);
  f32x4 wB = *reinterpret_cast<const f32x4*>(Wo + k0 + 4);
  float z = 0.f;
  #pragma unroll
  for (int j=0;j<4;j++){
    z += fmaxf(acc[0][j]  *di + bA[j], 0.f) * wA[j];
    z += fmaxf(acc[0][4+j]*di + bB[j], 0.f) * wB[j];
  }
  z += __shfl_xor(z, 16, 64);
  z += __shfl_xor(z, 32, 64);
  if (lg == 0){
    float sg = 1.f/(1.f + expf(-(z + bo[0])));
    tmp[(size_t)node*32 + rt*16 + l15] = sg;
  }
}

// ---------- transpose tmp [NT][32] -> out [32][NT] (coalesced writes) ----------
__global__ __launch_bounds__(256) void k_tr(const float* __restrict__ tmp, float* __restrict__ out){
  int n = blockIdx.x*256 + threadIdx.x;
  if (n < NT){
    f32x4 r[8];
    #pragma unroll
    for (int q=0;q<8;q++) r[q] = *reinterpret_cast<const f32x4*>(tmp + (size_t)n*32 + q*4);
    #pragma unroll
    for (int q=0;q<8;q++)
      #pragma unroll
      for (int j=0;j<4;j++)
        out[(size_t)(q*4+j)*NT + n] = r[q][j];
  }
}

// ---------- workspace layout (bytes); total ~164 MB (<= 213,784,016 proven) ----------
static constexpr size_t OFF_P    = 0;                         // P / Y3 alias: NT*2KB = 53,248,000
static constexpr size_t OFF_Q    = 53248000;                  // NT*4KB = 106,496,000
static constexpr size_t OFF_TMP  = 159744000;                 // NT*32*4 = 3,328,000
static constexpr size_t OFF_ZP   = 163072000;                 // 4 KB zero page
static constexpr size_t OFF_WT1  = OFF_ZP  + 4096;
static constexpr size_t OFF_WT2  = OFF_WT1 + 4096;
static constexpr size_t OFF_WT3  = OFF_WT2 + 8192;
static constexpr size_t OFF_DEG  = OFF_WT3 + 4096;
static constexpr size_t OFF_RP   = OFF_DEG + 104000;
static constexpr size_t OFF_CUR  = OFF_RP  + 104016;
static constexpr size_t OFF_COLS = OFF_CUR + 104000;
static constexpr size_t WS_NEED  = OFF_COLS + 448016;

extern "C" void kernel_launch(void* const* d_in, const int* in_sizes, int n_in,
                              void* d_out, int out_size, void* d_ws, size_t ws_size,
                              hipStream_t stream)
{
  const float* x    = (const float*)d_in[0];
  const int*   ei   = (const int*)  d_in[1];
  const int*   tidx = (const int*)  d_in[2];
  const float* emb  = (const float*)d_in[3];
  const float* W1   = (const float*)d_in[4];
  const float* b1   = (const float*)d_in[5];
  const float* W2   = (const float*)d_in[6];
  const float* b2   = (const float*)d_in[7];
  const float* W3   = (const float*)d_in[8];
  const float* b3   = (const float*)d_in[9];
  const float* Wo   = (const float*)d_in[10];
  const float* bo   = (const float*)d_in[11];
  float* out = (float*)d_out;

  if (ws_size < WS_NEED) return;

  char* ws = (char*)d_ws;
  uint32_t* P    = (uint32_t*)(ws + OFF_P);     // also Y3
  uint32_t* Q    = (uint32_t*)(ws + OFF_Q);
  float*    tmpf = (float*)   (ws + OFF_TMP);
  uint32_t* zp   = (uint32_t*)(ws + OFF_ZP);
  uint16_t* Wt1  = (uint16_t*)(ws + OFF_WT1);
  uint16_t* Wt2  = (uint16_t*)(ws + OFF_WT2);
  uint16_t* Wt3  = (uint16_t*)(ws + OFF_WT3);
  int*      deg  = (int*)     (ws + OFF_DEG);
  int*      rp   = (int*)     (ws + OFF_RP);
  int*      cur  = (int*)     (ws + OFF_CUR);
  uint16_t* cols = (uint16_t*)(ws + OFF_COLS);

  k_zero_deg<<<(NT+255)/256, 256, 0, stream>>>(deg);
  k_count   <<<(NE+255)/256, 256, 0, stream>>>(ei, deg);
  k_scan    <<<1, 1024, 0, stream>>>(deg, rp, cur);
  k_init    <<<442, 256, 0, stream>>>(zp, (uint32_t*)cols);
  k_fill    <<<(NE+255)/256, 256, 0, stream>>>(ei, cur, cols);
  k_prepw   <<<1, 256, 0, stream>>>(W1, W2, W3, Wt1, Wt2, Wt3);

  for (int ch = 0; ch < 2; ch++){
    k_build_h0<<<NT/16, 256, 0, stream>>>(x + (size_t)ch*32*NT*14, tidx, emb, P);
    k_layer1<<<NT/2, 256, 0, stream>>>(P, Q, rp, cur, cols, zp, Wt1, b1);
    k_l2g3  <<<NT/2, 256, 0, stream>>>(Q, P, rp, cur, cols, zp, Wt2, b2, Wt3);
    k_fin   <<<NT/2, 256, 0, stream>>>(P, rp, cur, cols, zp, b3, Wo, bo, tmpf);
    k_tr    <<<(NT+255)/256, 256, 0, stream>>>(tmpf, out + (size_t)ch*32*NT);
  }
}

// Round 9
// 523.835 us; speedup vs baseline: 1.5455x; 1.0698x over previous
//
#include <hip/hip_runtime.h>
#include <stdint.h>

static constexpr int NT = 26000;   // n_terms
static constexpr int NE = 120000;  // n_edges

typedef __attribute__((ext_vector_type(8))) short short8;   // 8 bf16 (MFMA A/B frag)
typedef __attribute__((ext_vector_type(4))) float f32x4;    // MFMA C/D frag

__device__ __forceinline__ int rfl(int v){ return __builtin_amdgcn_readfirstlane(v); }

// ---------- bf16 helpers ----------
__device__ __forceinline__ float bf_lo(uint32_t u){ union{uint32_t u; float f;} a; a.u = u<<16; return a.f; }
__device__ __forceinline__ float bf_hi(uint32_t u){ union{uint32_t u; float f;} a; a.u = u & 0xffff0000u; return a.f; }
__device__ __forceinline__ uint32_t f2b(float f){ union{float f; uint32_t u;} a; a.f=f; return (a.u + 0x7fffu + ((a.u>>16)&1u))>>16; }

// ---------- CSR build ----------
__global__ __launch_bounds__(256) void k_zero_deg(int* __restrict__ deg){
  int i = blockIdx.x*256 + threadIdx.x;
  if (i < NT) deg[i] = 0;
}
__global__ __launch_bounds__(256) void k_count(const int* __restrict__ ei, int* __restrict__ deg){
  int e = blockIdx.x*256 + threadIdx.x;
  if (e < NE) atomicAdd(&deg[ei[e]], 1);
}
// slots = max(4, ceil4(deg)); rp = prefix(slots); cur = rp
__global__ __launch_bounds__(1024) void k_scan(const int* __restrict__ deg, int* __restrict__ rp,
                                               int* __restrict__ cur){
  __shared__ int part[1024];
  const int t = threadIdx.x;
  const int CH = (NT + 1023)/1024;   // 26
  const int base = t*CH;
  int sum = 0;
  for (int i=0;i<CH;i++){
    int idx=base+i;
    if (idx<NT){ int d = deg[idx]; sum += (d<=4)?4:((d+3)&~3); }
  }
  part[t] = sum;
  __syncthreads();
  for (int off=1; off<1024; off<<=1){
    int v = (t>=off) ? part[t-off] : 0;
    __syncthreads();
    part[t] += v;
    __syncthreads();
  }
  int run = (t==0) ? 0 : part[t-1];
  for (int i=0;i<CH;i++){
    int idx = base+i;
    if (idx<NT){
      int d = deg[idx];
      int slot = (d<=4)?4:((d+3)&~3);
      rp[idx] = run; cur[idx] = run;
      run += slot;
    }
  }
  if (t==1023) rp[NT] = part[1023];
}
// init: zero page, cols sentinels, scale sentinels
__global__ __launch_bounds__(256) void k_init(uint32_t* __restrict__ zp, uint32_t* __restrict__ cols32,
                                              float* __restrict__ scQ, float* __restrict__ scY){
  int i = blockIdx.x*256 + threadIdx.x;
  if (i < 1024) zp[i] = 0;
  else if (i < 1024 + 112004) cols32[i-1024] = 0x65906590u;  // 26000 | 26000<<16
  if (i < 2){ scQ[NT*2+i] = 0.f; scY[NT*2+i] = 0.f; }
}
__global__ __launch_bounds__(256) void k_fill(const int* __restrict__ ei, int* __restrict__ cur,
                                              uint16_t* __restrict__ cols){
  int e = blockIdx.x*256 + threadIdx.x;
  if (e < NE){
    int r = ei[e];
    int pos = atomicAdd(&cur[r], 1);
    cols[pos] = (uint16_t)ei[NE + e];
  }
}
// pre-pack weights to bf16 [COUT][CIN] row-major, zero-padded K
__global__ __launch_bounds__(256) void k_prepw(const float* __restrict__ W1, const float* __restrict__ W2,
                                               const float* __restrict__ W3,
                                               uint16_t* __restrict__ Wt1, uint16_t* __restrict__ Wt2,
                                               uint16_t* __restrict__ Wt3){
  for (int idx = threadIdx.x; idx < 8192; idx += 256){
    if (idx < 2048){           // W1: 64 x 22 -> [64][32]
      int o = idx >> 5, k = idx & 31;
      Wt1[idx] = (uint16_t)((k < 22) ? f2b(W1[o*22 + k]) : 0);
    } else if (idx < 6144){    // W2: 64 x 64
      int j = idx - 2048;
      Wt2[j] = (uint16_t)f2b(W2[j]);
    } else {                   // W3: 32 x 64
      int j = idx - 6144;
      Wt3[j] = (uint16_t)f2b(W3[j]);
    }
  }
}

// ---------- build h0 (bf16 tiled, BB=32): [N] blocks of 32 rows x 32 k = 2KB ----------
__global__ __launch_bounds__(256) void k_build_h0(const float* __restrict__ x, const int* __restrict__ tidx,
                                                  const float* __restrict__ emb, uint32_t* __restrict__ h0){
  const int n  = blockIdx.x*16 + (threadIdx.x & 15);
  const int b0 = threadIdx.x >> 4;
  const float* er = emb + (size_t)tidx[n]*8;
  float ev[8];
  #pragma unroll
  for (int i=0;i<8;i++) ev[i]=er[i];
  uint32_t* dst = h0 + (size_t)n*512;

  #pragma unroll
  for (int h=0; h<2; h++){
    const int b = b0 + h*16;
    const float* xr = x + ((size_t)b*NT + n)*14;
    float v[32];
    #pragma unroll
    for (int i=0;i<14;i++) v[i]=xr[i];
    #pragma unroll
    for (int i=0;i<8;i++) v[14+i]=ev[i];
    #pragma unroll
    for (int i=22;i<32;i++) v[i]=0.f;
    uint32_t p[16];
    #pragma unroll
    for (int u=0;u<16;u++) p[u] = f2b(v[2*u]) | (f2b(v[2*u+1])<<16);
    const int base = (b>>4)*256 + (b&15)*8;
    *reinterpret_cast<uint4*>(dst + base)       = make_uint4(p[0],p[1],p[2],p[3]);
    *reinterpret_cast<uint4*>(dst + base + 4)   = make_uint4(p[4],p[5],p[6],p[7]);
    *reinterpret_cast<uint4*>(dst + base + 128)   = make_uint4(p[8],p[9],p[10],p[11]);
    *reinterpret_cast<uint4*>(dst + base + 132)   = make_uint4(p[12],p[13],p[14],p[15]);
  }
}

// ---------- bf16 gather machinery (layer 1 input) ----------
template<int STR>
__device__ __forceinline__ const uint32_t* nbp(const uint32_t* __restrict__ hin,
                                               const uint32_t* __restrict__ zp, int c){
  return (c < NT) ? (hin + (size_t)c*STR) : zp;
}
template<int KS>
__device__ __forceinline__ void gloadv(uint4 (&v)[KS], const uint32_t* __restrict__ p,
                                       const uint32_t (&off)[KS]){
  #pragma unroll
  for (int ks=0; ks<KS; ks++) v[ks] = *reinterpret_cast<const uint4*>(p + off[ks]);
}
template<int KS>
__device__ __forceinline__ void accum(float (&acc)[KS][8], const uint4 (&v)[KS]){
  #pragma unroll
  for (int ks=0;ks<KS;ks++){
    acc[ks][0]+=bf_lo(v[ks].x); acc[ks][1]+=bf_hi(v[ks].x);
    acc[ks][2]+=bf_lo(v[ks].y); acc[ks][3]+=bf_hi(v[ks].y);
    acc[ks][4]+=bf_lo(v[ks].z); acc[ks][5]+=bf_hi(v[ks].z);
    acc[ks][6]+=bf_lo(v[ks].w); acc[ks][7]+=bf_hi(v[ks].w);
  }
}
template<int KS, int STR>
__device__ __forceinline__ float aggregate(float (&acc)[KS][8],
    const uint32_t* __restrict__ hin, const uint32_t* __restrict__ zp,
    const int* __restrict__ rp, const int* __restrict__ cur,
    const uint16_t* __restrict__ cols, int node, const uint32_t (&off)[KS])
{
  const int e0 = rfl(rp[node]);
  const int e1 = rfl(rp[node+1]);
  const int dg = rfl(cur[node]) - e0;

  uint2 cc0 = *reinterpret_cast<const uint2*>(cols + e0);
  int q0 = rfl(cc0.x), q1 = rfl(cc0.y);
  uint4 v0[KS], v1[KS], v2[KS], v3[KS], own[KS];
  gloadv<KS>(v0, nbp<STR>(hin, zp, q0 & 0xffff), off);
  gloadv<KS>(v1, nbp<STR>(hin, zp, (q0 >> 16) & 0xffff), off);
  gloadv<KS>(v2, nbp<STR>(hin, zp, q1 & 0xffff), off);
  gloadv<KS>(v3, nbp<STR>(hin, zp, (q1 >> 16) & 0xffff), off);
  gloadv<KS>(own, hin + (size_t)node*STR, off);
  uint2 ccA = *reinterpret_cast<const uint2*>(cols + e0 + 4);

  const float degf = (float)(dg > 1 ? dg : 1);
  #pragma unroll
  for (int ks=0;ks<KS;ks++){
    acc[ks][0]=bf_lo(own[ks].x)*degf; acc[ks][1]=bf_hi(own[ks].x)*degf;
    acc[ks][2]=bf_lo(own[ks].y)*degf; acc[ks][3]=bf_hi(own[ks].y)*degf;
    acc[ks][4]=bf_lo(own[ks].z)*degf; acc[ks][5]=bf_hi(own[ks].z)*degf;
    acc[ks][6]=bf_lo(own[ks].w)*degf; acc[ks][7]=bf_hi(own[ks].w)*degf;
  }

  for (int e = e0; e < e1; e += 4){
    uint2 ccN = *reinterpret_cast<const uint2*>(cols + e + 8);
    int p0 = rfl(ccA.x), p1 = rfl(ccA.y);
    int n0 = (e+4 < e1) ? (p0 & 0xffff)         : NT;
    int n1 = (e+5 < e1) ? ((p0 >> 16) & 0xffff) : NT;
    int n2 = (e+6 < e1) ? (p1 & 0xffff)         : NT;
    int n3 = (e+7 < e1) ? ((p1 >> 16) & 0xffff) : NT;
    accum<KS>(acc, v0); gloadv<KS>(v0, nbp<STR>(hin, zp, n0), off);
    accum<KS>(acc, v1); gloadv<KS>(v1, nbp<STR>(hin, zp, n1), off);
    accum<KS>(acc, v2); gloadv<KS>(v2, nbp<STR>(hin, zp, n2), off);
    accum<KS>(acc, v3); gloadv<KS>(v3, nbp<STR>(hin, zp, n3), off);
    ccA = ccN;
  }
  return 1.0f / degf;
}

// ---------- i8 gather machinery (scaled dequant-accumulate) ----------
// Q block (2048B): byte(rt,row,k) = rt*1024 + row*64 + ((k>>3)&3)*16 + (k>>5)*8 + (k&7)
// Y3 block (1024B): byte(rt,row,k) = rt*512  + row*32 + ((k>>3)&3)*8 + (k&7)
template<int KS> struct VecT;
template<> struct VecT<2>{ using T = uint4; };
template<> struct VecT<1>{ using T = uint2; };

__device__ __forceinline__ void dqu32(float* a, uint32_t u, float s){
  a[0] += s*(float)(int8_t)(u & 0xff);
  a[1] += s*(float)(int8_t)((u>>8) & 0xff);
  a[2] += s*(float)(int8_t)((u>>16) & 0xff);
  a[3] += s*(float)(int8_t)(u>>24);
}
template<int KS>
__device__ __forceinline__ void dqv(float (&acc)[KS][8], const typename VecT<KS>::T& v, float s){
  if constexpr (KS==2){
    dqu32(&acc[0][0], v.x, s); dqu32(&acc[0][4], v.y, s);
    dqu32(&acc[1][0], v.z, s); dqu32(&acc[1][4], v.w, s);
  } else {
    dqu32(&acc[0][0], v.x, s); dqu32(&acc[0][4], v.y, s);
  }
}
template<int KS, int STRB>
__device__ __forceinline__ float aggregate_i8(float (&acc)[KS][8],
    const uint8_t* __restrict__ hin, const uint8_t* __restrict__ zp8,
    const float* __restrict__ sc,
    const int* __restrict__ rp, const int* __restrict__ cur,
    const uint16_t* __restrict__ cols, int node, uint32_t offB, int rt)
{
  using V = typename VecT<KS>::T;
  const int e0 = rfl(rp[node]);
  const int e1 = rfl(rp[node+1]);
  const int dg = rfl(cur[node]) - e0;

  uint2 cc0 = *reinterpret_cast<const uint2*>(cols + e0);
  int a0 = rfl(cc0.x), a1 = rfl(cc0.y);
  int c0 = a0 & 0xffff, c1 = (a0>>16) & 0xffff, c2 = a1 & 0xffff, c3 = (a1>>16) & 0xffff;
  auto bp = [&](int c)->const uint8_t*{ return (c < NT) ? (hin + (size_t)c*STRB) : zp8; };

  V v0 = *reinterpret_cast<const V*>(bp(c0) + offB); float s0 = sc[c0*2+rt];
  V v1 = *reinterpret_cast<const V*>(bp(c1) + offB); float s1 = sc[c1*2+rt];
  V v2 = *reinterpret_cast<const V*>(bp(c2) + offB); float s2 = sc[c2*2+rt];
  V v3 = *reinterpret_cast<const V*>(bp(c3) + offB); float s3 = sc[c3*2+rt];
  V ow = *reinterpret_cast<const V*>(hin + (size_t)node*STRB + offB);
  float so = sc[node*2+rt];
  uint2 ccA = *reinterpret_cast<const uint2*>(cols + e0 + 4);

  const float degf = (float)(dg > 1 ? dg : 1);
  #pragma unroll
  for (int ks=0;ks<KS;ks++)
    #pragma unroll
    for (int j=0;j<8;j++) acc[ks][j]=0.f;
  dqv<KS>(acc, ow, so*degf);

  for (int e = e0; e < e1; e += 4){
    uint2 ccN = *reinterpret_cast<const uint2*>(cols + e + 8);
    int p0 = rfl(ccA.x), p1 = rfl(ccA.y);
    int n0 = (e+4 < e1) ? (p0 & 0xffff)         : NT;
    int n1 = (e+5 < e1) ? ((p0 >> 16) & 0xffff) : NT;
    int n2 = (e+6 < e1) ? (p1 & 0xffff)         : NT;
    int n3 = (e+7 < e1) ? ((p1 >> 16) & 0xffff) : NT;
    dqv<KS>(acc, v0, s0); v0 = *reinterpret_cast<const V*>(bp(n0) + offB); s0 = sc[n0*2+rt];
    dqv<KS>(acc, v1, s1); v1 = *reinterpret_cast<const V*>(bp(n1) + offB); s1 = sc[n1*2+rt];
    dqv<KS>(acc, v2, s2); v2 = *reinterpret_cast<const V*>(bp(n2) + offB); s2 = sc[n2*2+rt];
    dqv<KS>(acc, v3, s3); v3 = *reinterpret_cast<const V*>(bp(n3) + offB); s3 = sc[n3*2+rt];
    ccA = ccN;
  }
  return 1.0f / degf;
}

// ---------- L1: gather(P bf16 32-wide) -> relu GEMM -> Q i8 + scQ ----------
__global__ __launch_bounds__(256, 8) void k_layer1(
    const uint32_t* __restrict__ hin, uint8_t* __restrict__ qout, float* __restrict__ scQ,
    const int* __restrict__ rp, const int* __restrict__ cur,
    const uint16_t* __restrict__ cols, const uint32_t* __restrict__ zp,
    const uint16_t* __restrict__ Wt, const float* __restrict__ bias)
{
  constexpr int CIN=32, STR=16*CIN;
  const int t=threadIdx.x, lane=t&63, w=t>>6, l15=lane&15, lg=lane>>4;
  const int rt = w & 1;
  const int node = blockIdx.x*2 + (w>>1);

  uint32_t off[1];
  off[0] = (uint32_t)(rt*(CIN*8) + (lg>>1)*128 + l15*8 + (lg&1)*4);

  float acc[1][8];
  const float di = aggregate<1,STR>(acc, hin, zp, rp, cur, cols, node, off);

  short8 bfrag;
  #pragma unroll
  for (int j=0;j<8;j++) bfrag[j] = (short)f2b(acc[0][j]*di);

  // GEMM + relu, collect values then quantize with wave-max scale
  float av[4][4];
  float m = 0.f;
  #pragma unroll
  for (int ot=0;ot<4;ot++){
    const int o0 = ot*16;
    short8 af = *reinterpret_cast<const short8*>(Wt + (o0 + l15)*CIN + lg*8);
    f32x4 d = *reinterpret_cast<const f32x4*>(bias + o0 + lg*4);
    d = __builtin_amdgcn_mfma_f32_16x16x32_bf16(af, bfrag, d, 0,0,0);
    #pragma unroll
    for (int j=0;j<4;j++){
      float v = fmaxf(d[j], 0.f);
      av[ot][j] = v;
      m = fmaxf(m, v);
    }
  }
  #pragma unroll
  for (int sh=1; sh<64; sh<<=1) m = fmaxf(m, __shfl_xor(m, sh, 64));
  const float inv = (m > 0.f) ? 127.0f/m : 0.f;

  uint8_t* base = qout + (size_t)node*2048 + rt*1024 + l15*64;
  #pragma unroll
  for (int ot=0;ot<4;ot++){
    uint32_t pk = 0;
    #pragma unroll
    for (int j=0;j<4;j++){
      int q = __float2int_rn(av[ot][j]*inv);
      pk |= (uint32_t)(q & 0xff) << (8*j);
    }
    uint32_t boff = ((((ot&1)<<1)|(lg>>1))<<4) + ((ot>>1)<<3) + ((lg&1)<<2);
    __builtin_nontemporal_store(pk, reinterpret_cast<uint32_t*>(base + boff));
  }
  if (lane == 0) scQ[node*2+rt] = m * (1.0f/127.0f);
}

// ---------- L2+G3 fused: gather(Q i8) -> relu GEMM(W2) -> LDS transpose -> GEMM(W3) -> Y3 i8 ----------
__global__ __launch_bounds__(256, 6) void k_l2g3(
    const uint8_t* __restrict__ qin, const float* __restrict__ scQ,
    uint8_t* __restrict__ yout, float* __restrict__ scY,
    const int* __restrict__ rp, const int* __restrict__ cur,
    const uint16_t* __restrict__ cols, const uint8_t* __restrict__ zp8,
    const uint16_t* __restrict__ Wt2, const float* __restrict__ bias,
    const uint16_t* __restrict__ Wt3)
{
  __shared__ uint32_t lt[4*512];
  const int t=threadIdx.x, lane=t&63, w=t>>6, l15=lane&15, lg=lane>>4;
  const int rt = w & 1;
  const int node = blockIdx.x*2 + (w>>1);

  const uint32_t offB = (uint32_t)(rt*1024 + l15*64 + lg*16);

  float acc[2][8];
  const float di = aggregate_i8<2,2048>(acc, qin, zp8, scQ, rp, cur, cols, node, offB, rt);

  short8 bfrag[2];
  #pragma unroll
  for (int ks=0;ks<2;ks++){
    short8 bf;
    #pragma unroll
    for (int j=0;j<8;j++) bf[j] = (short)f2b(acc[ks][j]*di);
    bfrag[ks]=bf;
  }

  // GEMM1: h2 = relu(W2 * s^T + b2) -> LDS tiled (bf16)
  uint32_t* L = lt + w*512;
  #pragma unroll
  for (int ot=0;ot<4;ot++){
    const int o0 = ot*16;
    short8 af0 = *reinterpret_cast<const short8*>(Wt2 + (o0 + l15)*64 + lg*8);
    short8 af1 = *reinterpret_cast<const short8*>(Wt2 + (o0 + l15)*64 + 32 + lg*8);
    f32x4 d = *reinterpret_cast<const f32x4*>(bias + o0 + lg*4);
    d = __builtin_amdgcn_mfma_f32_16x16x32_bf16(af0, bfrag[0], d, 0,0,0);
    d = __builtin_amdgcn_mfma_f32_16x16x32_bf16(af1, bfrag[1], d, 0,0,0);
    float a0=fmaxf(d[0],0.f), a1=fmaxf(d[1],0.f), a2=fmaxf(d[2],0.f), a3=fmaxf(d[3],0.f);
    *reinterpret_cast<uint2*>(L + ot*128 + l15*8 + lg*2) =
        make_uint2(f2b(a0) | (f2b(a1)<<16), f2b(a2) | (f2b(a3)<<16));
  }

  short8 b3f[2];
  #pragma unroll
  for (int ks=0;ks<2;ks++)
    b3f[ks] = *reinterpret_cast<const short8*>(L + (ks*2+(lg>>1))*128 + l15*8 + (lg&1)*4);

  // GEMM2: Y3 = W3 * h2^T -> i8 quantize (signed absmax)
  float dd[2][4];
  float m = 0.f;
  #pragma unroll
  for (int ot=0;ot<2;ot++){
    const int o0 = ot*16;
    short8 af0 = *reinterpret_cast<const short8*>(Wt3 + (o0 + l15)*64 + lg*8);
    short8 af1 = *reinterpret_cast<const short8*>(Wt3 + (o0 + l15)*64 + 32 + lg*8);
    f32x4 d = {0.f,0.f,0.f,0.f};
    d = __builtin_amdgcn_mfma_f32_16x16x32_bf16(af0, b3f[0], d, 0,0,0);
    d = __builtin_amdgcn_mfma_f32_16x16x32_bf16(af1, b3f[1], d, 0,0,0);
    #pragma unroll
    for (int j=0;j<4;j++){
      dd[ot][j] = d[j];
      m = fmaxf(m, fabsf(d[j]));
    }
  }
  #pragma unroll
  for (int sh=1; sh<64; sh<<=1) m = fmaxf(m, __shfl_xor(m, sh, 64));
  const float inv = (m > 0.f) ? 127.0f/m : 0.f;

  uint8_t* base = yout + (size_t)node*1024 + rt*512 + l15*32;
  #pragma unroll
  for (int ot=0;ot<2;ot++){
    uint32_t pk = 0;
    #pragma unroll
    for (int j=0;j<4;j++){
      int q = __float2int_rn(dd[ot][j]*inv);
      pk |= (uint32_t)(q & 0xff) << (8*j);
    }
    uint32_t boff = (((ot<<1)|(lg>>1))<<3) + ((lg&1)<<2);
    __builtin_nontemporal_store(pk, reinterpret_cast<uint32_t*>(base + boff));
  }
  if (lane == 0) scY[node*2+rt] = m * (1.0f/127.0f);
}

// ---------- final: aggregate Y3 (i8 32-wide) + b3 + relu + head dot + sigmoid ----------
__global__ __launch_bounds__(256, 8) void k_fin(
    const uint8_t* __restrict__ yin, const float* __restrict__ scY,
    const int* __restrict__ rp, const int* __restrict__ cur,
    const uint16_t* __restrict__ cols, const uint8_t* __restrict__ zp8,
    const float* __restrict__ b3, const float* __restrict__ Wo, const float* __restrict__ bo,
    float* __restrict__ tmp)            // [NT][32] f32
{
  const int t=threadIdx.x, lane=t&63, w=t>>6, l15=lane&15, lg=lane>>4;
  const int rt = w & 1;
  const int node = blockIdx.x*2 + (w>>1);

  const uint32_t offB = (uint32_t)(rt*512 + l15*32 + lg*8);

  float acc[1][8];
  const float di = aggregate_i8<1,1024>(acc, yin, zp8, scY, rp, cur, cols, node, offB, rt);

  const int k0 = lg*8;
  f32x4 bA = *reinterpret_cast<const f32x4*>(b3 + k0);
  f32x4 bB = *reinterpret_cast<const f32x4*>(b3 + k0 + 4);
  f32x4 wA = *reinterpret_cast<const f32x4*>(Wo + k0);
  f32x4 wB = *reinterpret_cast<const f32x4*>(Wo + k0 + 4);
  float z = 0.f;
  #pragma unroll
  for (int j=0;j<4;j++){
    z += fmaxf(acc[0][j]  *di + bA[j], 0.f) * wA[j];
    z += fmaxf(acc[0][4+j]*di + bB[j], 0.f) * wB[j];
  }
  z += __shfl_xor(z, 16, 64);
  z += __shfl_xor(z, 32, 64);
  if (lg == 0){
    float sg = 1.f/(1.f + expf(-(z + bo[0])));
    tmp[(size_t)node*32 + rt*16 + l15] = sg;
  }
}

// ---------- transpose tmp [NT][32] -> out [32][NT] ----------
__global__ __launch_bounds__(256) void k_tr(const float* __restrict__ tmp, float* __restrict__ out){
  int n = blockIdx.x*256 + threadIdx.x;
  if (n < NT){
    f32x4 r[8];
    #pragma unroll
    for (int q=0;q<8;q++) r[q] = *reinterpret_cast<const f32x4*>(tmp + (size_t)n*32 + q*4);
    #pragma unroll
    for (int q=0;q<8;q++)
      #pragma unroll
      for (int j=0;j<4;j++)
        out[(size_t)(q*4+j)*NT + n] = r[q][j];
  }
}

// ---------- workspace layout (bytes); ~111 MB ----------
static constexpr size_t OFF_P    = 0;                          // bf16 h0: NT*2048 = 53,248,000 (Y3 aliases)
static constexpr size_t OFF_Q    = 53248000;                   // i8 h1: NT*2048 = 53,248,000
static constexpr size_t OFF_TMP  = 106496000;                  // NT*32*4 = 3,328,000
static constexpr size_t OFF_ZP   = 109824000;                  // 4 KB zero page
static constexpr size_t OFF_WT1  = OFF_ZP  + 4096;
static constexpr size_t OFF_WT2  = OFF_WT1 + 4096;
static constexpr size_t OFF_WT3  = OFF_WT2 + 8192;
static constexpr size_t OFF_SCQ  = OFF_WT3 + 4096;             // (NT+1)*2 f32 = 208,008 -> 208,016
static constexpr size_t OFF_SCY  = OFF_SCQ + 208016;
static constexpr size_t OFF_DEG  = OFF_SCY + 208016;
static constexpr size_t OFF_RP   = OFF_DEG + 104000;
static constexpr size_t OFF_CUR  = OFF_RP  + 104016;
static constexpr size_t OFF_COLS = OFF_CUR + 104000;
static constexpr size_t WS_NEED  = OFF_COLS + 448016;

extern "C" void kernel_launch(void* const* d_in, const int* in_sizes, int n_in,
                              void* d_out, int out_size, void* d_ws, size_t ws_size,
                              hipStream_t stream)
{
  const float* x    = (const float*)d_in[0];
  const int*   ei   = (const int*)  d_in[1];
  const int*   tidx = (const int*)  d_in[2];
  const float* emb  = (const float*)d_in[3];
  const float* W1   = (const float*)d_in[4];
  const float* b1   = (const float*)d_in[5];
  const float* W2   = (const float*)d_in[6];
  const float* b2   = (const float*)d_in[7];
  const float* W3   = (const float*)d_in[8];
  const float* b3   = (const float*)d_in[9];
  const float* Wo   = (const float*)d_in[10];
  const float* bo   = (const float*)d_in[11];
  float* out = (float*)d_out;

  if (ws_size < WS_NEED) return;

  char* ws = (char*)d_ws;
  uint32_t* P    = (uint32_t*)(ws + OFF_P);
  uint8_t*  Y3   = (uint8_t*) (ws + OFF_P);     // aliases P (h0 dead after layer1)
  uint8_t*  Q    = (uint8_t*) (ws + OFF_Q);
  float*    tmpf = (float*)   (ws + OFF_TMP);
  uint32_t* zp   = (uint32_t*)(ws + OFF_ZP);
  uint8_t*  zp8  = (uint8_t*) (ws + OFF_ZP);
  uint16_t* Wt1  = (uint16_t*)(ws + OFF_WT1);
  uint16_t* Wt2  = (uint16_t*)(ws + OFF_WT2);
  uint16_t* Wt3  = (uint16_t*)(ws + OFF_WT3);
  float*    scQ  = (float*)   (ws + OFF_SCQ);
  float*    scY  = (float*)   (ws + OFF_SCY);
  int*      deg  = (int*)     (ws + OFF_DEG);
  int*      rp   = (int*)     (ws + OFF_RP);
  int*      cur  = (int*)     (ws + OFF_CUR);
  uint16_t* cols = (uint16_t*)(ws + OFF_COLS);

  k_zero_deg<<<(NT+255)/256, 256, 0, stream>>>(deg);
  k_count   <<<(NE+255)/256, 256, 0, stream>>>(ei, deg);
  k_scan    <<<1, 1024, 0, stream>>>(deg, rp, cur);
  k_init    <<<442, 256, 0, stream>>>(zp, (uint32_t*)cols, scQ, scY);
  k_fill    <<<(NE+255)/256, 256, 0, stream>>>(ei, cur, cols);
  k_prepw   <<<1, 256, 0, stream>>>(W1, W2, W3, Wt1, Wt2, Wt3);

  for (int ch = 0; ch < 2; ch++){
    k_build_h0<<<NT/16, 256, 0, stream>>>(x + (size_t)ch*32*NT*14, tidx, emb, P);
    k_layer1<<<NT/2, 256, 0, stream>>>(P, Q, scQ, rp, cur, cols, zp, Wt1, b1);
    k_l2g3  <<<NT/2, 256, 0, stream>>>(Q, scQ, Y3, scY, rp, cur, cols, zp8, Wt2, b2, Wt3);
    k_fin   <<<NT/2, 256, 0, stream>>>(Y3, scY, rp, cur, cols, zp8, b3, Wo, bo, tmpf);
    k_tr    <<<(NT+255)/256, 256, 0, stream>>>(tmpf, out + (size_t)ch*32*NT);
  }
}

// Round 11
// 500.979 us; speedup vs baseline: 1.6160x; 1.0456x over previous
//
#include <hip/hip_runtime.h>
#include <stdint.h>

static constexpr int NT = 26000;   // n_terms
static constexpr int NE = 120000;  // n_edges

typedef __attribute__((ext_vector_type(8))) short short8;   // 8 bf16 (MFMA A/B frag)
typedef __attribute__((ext_vector_type(4))) float f32x4;    // MFMA C/D frag
typedef __attribute__((ext_vector_type(4))) unsigned int u32x4;

__device__ __forceinline__ int rfl(int v){ return __builtin_amdgcn_readfirstlane(v); }

// ---------- bf16 helpers ----------
__device__ __forceinline__ float bf_lo(uint32_t u){ union{uint32_t u; float f;} a; a.u = u<<16; return a.f; }
__device__ __forceinline__ float bf_hi(uint32_t u){ union{uint32_t u; float f;} a; a.u = u & 0xffff0000u; return a.f; }
__device__ __forceinline__ uint32_t f2b(float f){ union{float f; uint32_t u;} a; a.f=f; return (a.u + 0x7fffu + ((a.u>>16)&1u))>>16; }

__device__ __forceinline__ void nts4(uint8_t* p, uint32_t a, uint32_t b, uint32_t c, uint32_t d){
  u32x4 v; v.x=a; v.y=b; v.z=c; v.w=d;
  __builtin_nontemporal_store(v, reinterpret_cast<u32x4*>(p));
}

// ---------- CSR build ----------
__global__ __launch_bounds__(256) void k_zero_deg(int* __restrict__ deg){
  int i = blockIdx.x*256 + threadIdx.x;
  if (i < NT) deg[i] = 0;
}
__global__ __launch_bounds__(256) void k_count(const int* __restrict__ ei, int* __restrict__ deg){
  int e = blockIdx.x*256 + threadIdx.x;
  if (e < NE) atomicAdd(&deg[ei[e]], 1);
}
// slots = max(4, ceil4(deg)); rp = prefix(slots); cur = rp
__global__ __launch_bounds__(1024) void k_scan(const int* __restrict__ deg, int* __restrict__ rp,
                                               int* __restrict__ cur){
  __shared__ int part[1024];
  const int t = threadIdx.x;
  const int CH = (NT + 1023)/1024;   // 26
  const int base = t*CH;
  int sum = 0;
  for (int i=0;i<CH;i++){
    int idx=base+i;
    if (idx<NT){ int d = deg[idx]; sum += (d<=4)?4:((d+3)&~3); }
  }
  part[t] = sum;
  __syncthreads();
  for (int off=1; off<1024; off<<=1){
    int v = (t>=off) ? part[t-off] : 0;
    __syncthreads();
    part[t] += v;
    __syncthreads();
  }
  int run = (t==0) ? 0 : part[t-1];
  for (int i=0;i<CH;i++){
    int idx = base+i;
    if (idx<NT){
      int d = deg[idx];
      int slot = (d<=4)?4:((d+3)&~3);
      rp[idx] = run; cur[idx] = run;
      run += slot;
    }
  }
  if (t==1023) rp[NT] = part[1023];
}
// init: zero page, cols sentinels, scale sentinels (index NT -> scale 0)
__global__ __launch_bounds__(256) void k_init(uint32_t* __restrict__ zp, uint32_t* __restrict__ cols32,
                                              float* __restrict__ scP, float* __restrict__ scQ,
                                              float* __restrict__ scY){
  int i = blockIdx.x*256 + threadIdx.x;
  if (i < 1024) zp[i] = 0;
  else if (i < 1024 + 112004) cols32[i-1024] = 0x65906590u;  // 26000 | 26000<<16
  if (i < 2){ scP[NT*2+i] = 0.f; scQ[NT*2+i] = 0.f; scY[NT*2+i] = 0.f; }
}
__global__ __launch_bounds__(256) void k_fill(const int* __restrict__ ei, int* __restrict__ cur,
                                              uint16_t* __restrict__ cols){
  int e = blockIdx.x*256 + threadIdx.x;
  if (e < NE){
    int r = ei[e];
    int pos = atomicAdd(&cur[r], 1);
    cols[pos] = (uint16_t)ei[NE + e];
  }
}
// pre-pack weights to bf16 [COUT][CIN] row-major, zero-padded K
__global__ __launch_bounds__(256) void k_prepw(const float* __restrict__ W1, const float* __restrict__ W2,
                                               const float* __restrict__ W3,
                                               uint16_t* __restrict__ Wt1, uint16_t* __restrict__ Wt2,
                                               uint16_t* __restrict__ Wt3){
  for (int idx = threadIdx.x; idx < 8192; idx += 256){
    if (idx < 2048){           // W1: 64 x 22 -> [64][32]
      int o = idx >> 5, k = idx & 31;
      Wt1[idx] = (uint16_t)((k < 22) ? f2b(W1[o*22 + k]) : 0);
    } else if (idx < 6144){    // W2: 64 x 64
      int j = idx - 2048;
      Wt2[j] = (uint16_t)f2b(W2[j]);
    } else {                   // W3: 32 x 64
      int j = idx - 6144;
      Wt3[j] = (uint16_t)f2b(W3[j]);
    }
  }
}

// ---------- build h0 as biased-u8: [N] blocks [2 half][16 row][32 ch] = 1KB; scP per (node,half) ----------
__global__ __launch_bounds__(256) void k_build_h0(const float* __restrict__ x, const int* __restrict__ tidx,
                                                  const float* __restrict__ emb,
                                                  uint8_t* __restrict__ p8, float* __restrict__ scP){
  __shared__ float red[2][16][16];   // [half][row][node-in-block]
  __shared__ float sinv[2][16];
  const int t  = threadIdx.x;
  const int ni = t & 15;
  const int n  = blockIdx.x*16 + ni;
  const int r  = t >> 4;
  const float* er = emb + (size_t)tidx[n]*8;
  float ev[8];
  #pragma unroll
  for (int i=0;i<8;i++) ev[i]=er[i];

  float v[2][32];
  #pragma unroll
  for (int rt=0; rt<2; rt++){
    const int b = r + rt*16;
    const float* xr = x + ((size_t)b*NT + n)*14;
    float m = 0.f;
    #pragma unroll
    for (int i=0;i<14;i++){ float a=xr[i]; v[rt][i]=a; m=fmaxf(m,fabsf(a)); }
    #pragma unroll
    for (int i=0;i<8;i++){ float a=ev[i]; v[rt][14+i]=a; m=fmaxf(m,fabsf(a)); }
    #pragma unroll
    for (int i=22;i<32;i++) v[rt][i]=0.f;
    red[rt][r][ni] = m;
  }
  __syncthreads();
  if (t < 32){
    int rt = t >> 4, nn = t & 15;
    float mm = 0.f;
    #pragma unroll
    for (int i=0;i<16;i++) mm = fmaxf(mm, red[rt][i][nn]);
    sinv[rt][nn] = (mm > 0.f) ? 127.0f/mm : 0.f;
    scP[(size_t)(blockIdx.x*16+nn)*2 + rt] = mm * (1.0f/127.0f);
  }
  __syncthreads();

  uint8_t* dst = p8 + (size_t)n*1024;
  #pragma unroll
  for (int rt=0; rt<2; rt++){
    const float inv = sinv[rt][ni];
    uint32_t pk[8];
    #pragma unroll
    for (int u=0;u<8;u++){
      uint32_t w = 0;
      #pragma unroll
      for (int j=0;j<4;j++){
        int q = __float2int_rn(v[rt][u*4+j]*inv) + 128;
        q = q < 0 ? 0 : (q > 255 ? 255 : q);
        w |= (uint32_t)q << (8*j);
      }
      pk[u] = w;
    }
    nts4(dst + rt*512 + r*32,      pk[0],pk[1],pk[2],pk[3]);
    nts4(dst + rt*512 + r*32 + 16, pk[4],pk[5],pk[6],pk[7]);
  }
}

// ---------- quantized gather machinery ----------
template<int KS> struct VecT;
template<> struct VecT<2>{ using T = uint4; };
template<> struct VecT<1>{ using T = uint2; };

__device__ __forceinline__ void dq_u(float* a, uint32_t u, float s){
  a[0] += s*(float)(u & 0xffu);
  a[1] += s*(float)((u>>8) & 0xffu);
  a[2] += s*(float)((u>>16) & 0xffu);
  a[3] += s*(float)(u>>24);
}
__device__ __forceinline__ void dq_s(float* a, uint32_t u, float s){
  a[0] += s*(float)(int8_t)(u & 0xff);
  a[1] += s*(float)(int8_t)((u>>8) & 0xff);
  a[2] += s*(float)(int8_t)((u>>16) & 0xff);
  a[3] += s*(float)(int8_t)(u>>24);
}
template<int KS, bool SG>
__device__ __forceinline__ void dqv(float (&acc)[KS][8], const typename VecT<KS>::T& v, float s){
  if constexpr (KS==2){
    if constexpr (SG){ dq_s(&acc[0][0],v.x,s); dq_s(&acc[0][4],v.y,s); dq_s(&acc[1][0],v.z,s); dq_s(&acc[1][4],v.w,s); }
    else             { dq_u(&acc[0][0],v.x,s); dq_u(&acc[0][4],v.y,s); dq_u(&acc[1][0],v.z,s); dq_u(&acc[1][4],v.w,s); }
  } else {
    if constexpr (SG){ dq_s(&acc[0][0],v.x,s); dq_s(&acc[0][4],v.y,s); }
    else             { dq_u(&acc[0][0],v.x,s); dq_u(&acc[0][4],v.y,s); }
  }
}

// MODE: 0 = unsigned u8 (no bias), 1 = biased u8 (track sumS), 2 = signed i8
template<int KS, int STRB, int MODE>
__device__ __forceinline__ float aggregate_q(float (&acc)[KS][8], float& sumS,
    const uint8_t* __restrict__ hin, const uint8_t* __restrict__ zp8,
    const float* __restrict__ sc,
    const int* __restrict__ rp, const int* __restrict__ cur,
    const uint16_t* __restrict__ cols, int node, uint32_t offB, int rt)
{
  using V = typename VecT<KS>::T;
  constexpr bool SG = (MODE==2);
  const int e0 = rfl(rp[node]);
  const int e1 = rfl(rp[node+1]);
  const int dg = rfl(cur[node]) - e0;

  uint2 cc0 = *reinterpret_cast<const uint2*>(cols + e0);
  int a0 = rfl(cc0.x), a1 = rfl(cc0.y);
  int c0 = a0 & 0xffff, c1 = (a0>>16) & 0xffff, c2 = a1 & 0xffff, c3 = (a1>>16) & 0xffff;
  auto bp = [&](int c)->const uint8_t*{ return (c < NT) ? (hin + (size_t)c*STRB) : zp8; };

  V v0 = *reinterpret_cast<const V*>(bp(c0) + offB); float s0 = sc[c0*2+rt];
  V v1 = *reinterpret_cast<const V*>(bp(c1) + offB); float s1 = sc[c1*2+rt];
  V v2 = *reinterpret_cast<const V*>(bp(c2) + offB); float s2 = sc[c2*2+rt];
  V v3 = *reinterpret_cast<const V*>(bp(c3) + offB); float s3 = sc[c3*2+rt];
  V ow = *reinterpret_cast<const V*>(hin + (size_t)node*STRB + offB);
  float so = sc[node*2+rt];
  uint2 ccA = *reinterpret_cast<const uint2*>(cols + e0 + 4);

  const float degf = (float)(dg > 1 ? dg : 1);
  #pragma unroll
  for (int ks=0;ks<KS;ks++)
    #pragma unroll
    for (int j=0;j<8;j++) acc[ks][j]=0.f;
  dqv<KS,SG>(acc, ow, so*degf);
  if constexpr (MODE==1) sumS = so*degf;

  for (int e = e0; e < e1; e += 4){
    uint2 ccN = *reinterpret_cast<const uint2*>(cols + e + 8);   // 8 sentinels at end
    int p0 = rfl(ccA.x), p1 = rfl(ccA.y);
    int n0 = (e+4 < e1) ? (p0 & 0xffff)         : NT;
    int n1 = (e+5 < e1) ? ((p0 >> 16) & 0xffff) : NT;
    int n2 = (e+6 < e1) ? (p1 & 0xffff)         : NT;
    int n3 = (e+7 < e1) ? ((p1 >> 16) & 0xffff) : NT;
    dqv<KS,SG>(acc, v0, s0); if constexpr (MODE==1) sumS += s0;
    v0 = *reinterpret_cast<const V*>(bp(n0) + offB); s0 = sc[n0*2+rt];
    dqv<KS,SG>(acc, v1, s1); if constexpr (MODE==1) sumS += s1;
    v1 = *reinterpret_cast<const V*>(bp(n1) + offB); s1 = sc[n1*2+rt];
    dqv<KS,SG>(acc, v2, s2); if constexpr (MODE==1) sumS += s2;
    v2 = *reinterpret_cast<const V*>(bp(n2) + offB); s2 = sc[n2*2+rt];
    dqv<KS,SG>(acc, v3, s3); if constexpr (MODE==1) sumS += s3;
    v3 = *reinterpret_cast<const V*>(bp(n3) + offB); s3 = sc[n3*2+rt];
    ccA = ccN;
  }
  return 1.0f / degf;
}

// ---------- L1: gather(h0 u8-biased 32ch) -> relu GEMM(W1) -> Q u8-unsigned + scQ ----------
__global__ __launch_bounds__(256, 8) void k_layer1(
    const uint8_t* __restrict__ pin, const float* __restrict__ scP,
    uint8_t* __restrict__ qout, float* __restrict__ scQ,
    const int* __restrict__ rp, const int* __restrict__ cur,
    const uint16_t* __restrict__ cols, const uint8_t* __restrict__ zp8,
    const uint16_t* __restrict__ Wt, const float* __restrict__ bias)
{
  const int t=threadIdx.x, lane=t&63, w=t>>6, l15=lane&15, lg=lane>>4;
  const int rt = w & 1;
  const int node = blockIdx.x*2 + (w>>1);

  const uint32_t offB = (uint32_t)(rt*512 + l15*32 + lg*8);

  float acc[1][8]; float sumS = 0.f;
  const float di = aggregate_q<1,1024,1>(acc, sumS, pin, zp8, scP, rp, cur, cols, node, offB, rt);
  const float corr = 128.0f * sumS;

  short8 bfrag;
  #pragma unroll
  for (int j=0;j<8;j++) bfrag[j] = (short)f2b((acc[0][j] - corr)*di);

  // GEMM(W1) + relu, then unsigned-u8 quantize with wave-max scale
  float av[4][4];
  float m = 0.f;
  #pragma unroll
  for (int ot=0;ot<4;ot++){
    const int o0 = ot*16;
    short8 af = *reinterpret_cast<const short8*>(Wt + (o0 + l15)*32 + lg*8);
    f32x4 d = *reinterpret_cast<const f32x4*>(bias + o0 + lg*4);
    d = __builtin_amdgcn_mfma_f32_16x16x32_bf16(af, bfrag, d, 0,0,0);
    #pragma unroll
    for (int j=0;j<4;j++){
      float v = fmaxf(d[j], 0.f);
      av[ot][j] = v;
      m = fmaxf(m, v);
    }
  }
  #pragma unroll
  for (int sh=1; sh<64; sh<<=1) m = fmaxf(m, __shfl_xor(m, sh, 64));
  const float inv = (m > 0.f) ? 255.0f/m : 0.f;

  uint8_t* base = qout + (size_t)node*2048 + rt*1024 + l15*64;
  #pragma unroll
  for (int ot=0;ot<4;ot++){
    uint32_t pk = 0;
    #pragma unroll
    for (int j=0;j<4;j++){
      int q = __float2int_rn(av[ot][j]*inv);
      q = q > 255 ? 255 : q;
      pk |= (uint32_t)q << (8*j);
    }
    uint32_t boff = ((((ot&1)<<1)|(lg>>1))<<4) + ((ot>>1)<<3) + ((lg&1)<<2);
    __builtin_nontemporal_store(pk, reinterpret_cast<uint32_t*>(base + boff));
  }
  if (lane == 0) scQ[node*2+rt] = m * (1.0f/255.0f);
}

// ---------- L2+G3 fused: gather(Q u8 64ch) -> relu GEMM(W2) -> LDS transpose -> GEMM(W3) -> Y3 i8 ----------
__global__ __launch_bounds__(256, 6) void k_l2g3(
    const uint8_t* __restrict__ qin, const float* __restrict__ scQ,
    uint8_t* __restrict__ yout, float* __restrict__ scY,
    const int* __restrict__ rp, const int* __restrict__ cur,
    const uint16_t* __restrict__ cols, const uint8_t* __restrict__ zp8,
    const uint16_t* __restrict__ Wt2, const float* __restrict__ bias,
    const uint16_t* __restrict__ Wt3)
{
  __shared__ uint32_t lt[4*512];
  const int t=threadIdx.x, lane=t&63, w=t>>6, l15=lane&15, lg=lane>>4;
  const int rt = w & 1;
  const int node = blockIdx.x*2 + (w>>1);

  const uint32_t offB = (uint32_t)(rt*1024 + l15*64 + lg*16);

  float acc[2][8]; float dummy;
  const float di = aggregate_q<2,2048,0>(acc, dummy, qin, zp8, scQ, rp, cur, cols, node, offB, rt);

  short8 bfrag[2];
  #pragma unroll
  for (int ks=0;ks<2;ks++){
    short8 bf;
    #pragma unroll
    for (int j=0;j<8;j++) bf[j] = (short)f2b(acc[ks][j]*di);
    bfrag[ks]=bf;
  }

  // GEMM1: h2 = relu(W2 * s^T + b2) -> LDS tiled (bf16)
  uint32_t* L = lt + w*512;
  #pragma unroll
  for (int ot=0;ot<4;ot++){
    const int o0 = ot*16;
    short8 af0 = *reinterpret_cast<const short8*>(Wt2 + (o0 + l15)*64 + lg*8);
    short8 af1 = *reinterpret_cast<const short8*>(Wt2 + (o0 + l15)*64 + 32 + lg*8);
    f32x4 d = *reinterpret_cast<const f32x4*>(bias + o0 + lg*4);
    d = __builtin_amdgcn_mfma_f32_16x16x32_bf16(af0, bfrag[0], d, 0,0,0);
    d = __builtin_amdgcn_mfma_f32_16x16x32_bf16(af1, bfrag[1], d, 0,0,0);
    float a0=fmaxf(d[0],0.f), a1=fmaxf(d[1],0.f), a2=fmaxf(d[2],0.f), a3=fmaxf(d[3],0.f);
    *reinterpret_cast<uint2*>(L + ot*128 + l15*8 + lg*2) =
        make_uint2(f2b(a0) | (f2b(a1)<<16), f2b(a2) | (f2b(a3)<<16));
  }

  short8 b3f[2];
  #pragma unroll
  for (int ks=0;ks<2;ks++)
    b3f[ks] = *reinterpret_cast<const short8*>(L + (ks*2+(lg>>1))*128 + l15*8 + (lg&1)*4);

  // GEMM2: Y3 = W3 * h2^T -> signed i8 quantize
  float dd[2][4];
  float m = 0.f;
  #pragma unroll
  for (int ot=0;ot<2;ot++){
    const int o0 = ot*16;
    short8 af0 = *reinterpret_cast<const short8*>(Wt3 + (o0 + l15)*64 + lg*8);
    short8 af1 = *reinterpret_cast<const short8*>(Wt3 + (o0 + l15)*64 + 32 + lg*8);
    f32x4 d = {0.f,0.f,0.f,0.f};
    d = __builtin_amdgcn_mfma_f32_16x16x32_bf16(af0, b3f[0], d, 0,0,0);
    d = __builtin_amdgcn_mfma_f32_16x16x32_bf16(af1, b3f[1], d, 0,0,0);
    #pragma unroll
    for (int j=0;j<4;j++){
      dd[ot][j] = d[j];
      m = fmaxf(m, fabsf(d[j]));
    }
  }
  #pragma unroll
  for (int sh=1; sh<64; sh<<=1) m = fmaxf(m, __shfl_xor(m, sh, 64));
  const float inv = (m > 0.f) ? 127.0f/m : 0.f;

  uint8_t* base = yout + (size_t)node*1024 + rt*512 + l15*32;
  #pragma unroll
  for (int ot=0;ot<2;ot++){
    uint32_t pk = 0;
    #pragma unroll
    for (int j=0;j<4;j++){
      int q = __float2int_rn(dd[ot][j]*inv);
      pk |= (uint32_t)(q & 0xff) << (8*j);
    }
    uint32_t boff = (((ot<<1)|(lg>>1))<<3) + ((lg&1)<<2);
    __builtin_nontemporal_store(pk, reinterpret_cast<uint32_t*>(base + boff));
  }
  if (lane == 0) scY[node*2+rt] = m * (1.0f/127.0f);
}

// ---------- final: aggregate Y3 (i8 32ch) + b3 + relu + head dot + sigmoid ----------
__global__ __launch_bounds__(256, 8) void k_fin(
    const uint8_t* __restrict__ yin, const float* __restrict__ scY,
    const int* __restrict__ rp, const int* __restrict__ cur,
    const uint16_t* __restrict__ cols, const uint8_t* __restrict__ zp8,
    const float* __restrict__ b3, const float* __restrict__ Wo, const float* __restrict__ bo,
    float* __restrict__ tmp)            // [NT][32] f32
{
  const int t=threadIdx.x, lane=t&63, w=t>>6, l15=lane&15, lg=lane>>4;
  const int rt = w & 1;
  const int node = blockIdx.x*2 + (w>>1);

  const uint32_t offB = (uint32_t)(rt*512 + l15*32 + lg*8);

  float acc[1][8]; float dummy;
  const float di = aggregate_q<1,1024,2>(acc, dummy, yin, zp8, scY, rp, cur, cols, node, offB, rt);

  const int k0 = lg*8;
  f32x4 bA = *reinterpret_cast<const f32x4*>(b3 + k0);
  f32x4 bB = *reinterpret_cast<const f32x4*>(b3 + k0 + 4);
  f32x4 wA = *reinterpret_cast<const f32x4*>(Wo + k0);
  f32x4 wB = *reinterpret_cast<const f32x4*>(Wo + k0 + 4);
  float z = 0.f;
  #pragma unroll
  for (int j=0;j<4;j++){
    z += fmaxf(acc[0][j]  *di + bA[j], 0.f) * wA[j];
    z += fmaxf(acc[0][4+j]*di + bB[j], 0.f) * wB[j];
  }
  z += __shfl_xor(z, 16, 64);
  z += __shfl_xor(z, 32, 64);
  if (lg == 0){
    float sg = 1.f/(1.f + expf(-(z + bo[0])));
    tmp[(size_t)node*32 + rt*16 + l15] = sg;
  }
}

// ---------- transpose tmp [NT][32] -> out [32][NT] ----------
__global__ __launch_bounds__(256) void k_tr(const float* __restrict__ tmp, float* __restrict__ out){
  int n = blockIdx.x*256 + threadIdx.x;
  if (n < NT){
    f32x4 r[8];
    #pragma unroll
    for (int q=0;q<8;q++) r[q] = *reinterpret_cast<const f32x4*>(tmp + (size_t)n*32 + q*4);
    #pragma unroll
    for (int q=0;q<8;q++)
      #pragma unroll
      for (int j=0;j<4;j++)
        out[(size_t)(q*4+j)*NT + n] = r[q][j];
  }
}

// ---------- workspace layout (bytes); ~85 MB ----------
static constexpr size_t OFF_P    = 0;                          // h0 u8: NT*1024 (Y3 aliases after L1)
static constexpr size_t OFF_Q    = 26624000;                   // Q u8: NT*2048
static constexpr size_t OFF_TMP  = 79872000;                   // NT*32*4 = 3,328,000
static constexpr size_t OFF_ZP   = 83200000;                   // 4 KB zero page
static constexpr size_t OFF_WT1  = OFF_ZP  + 4096;
static constexpr size_t OFF_WT2  = OFF_WT1 + 4096;
static constexpr size_t OFF_WT3  = OFF_WT2 + 8192;
static constexpr size_t OFF_SCP  = OFF_WT3 + 4096;             // (NT*2+2)*4 -> 208,016
static constexpr size_t OFF_SCQ  = OFF_SCP + 208016;
static constexpr size_t OFF_SCY  = OFF_SCQ + 208016;
static constexpr size_t OFF_DEG  = OFF_SCY + 208016;
static constexpr size_t OFF_RP   = OFF_DEG + 104000;
static constexpr size_t OFF_CUR  = OFF_RP  + 104016;
static constexpr size_t OFF_COLS = OFF_CUR + 104000;
static constexpr size_t WS_NEED  = OFF_COLS + 448016;

extern "C" void kernel_launch(void* const* d_in, const int* in_sizes, int n_in,
                              void* d_out, int out_size, void* d_ws, size_t ws_size,
                              hipStream_t stream)
{
  const float* x    = (const float*)d_in[0];
  const int*   ei   = (const int*)  d_in[1];
  const int*   tidx = (const int*)  d_in[2];
  const float* emb  = (const float*)d_in[3];
  const float* W1   = (const float*)d_in[4];
  const float* b1   = (const float*)d_in[5];
  const float* W2   = (const float*)d_in[6];
  const float* b2   = (const float*)d_in[7];
  const float* W3   = (const float*)d_in[8];
  const float* b3   = (const float*)d_in[9];
  const float* Wo   = (const float*)d_in[10];
  const float* bo   = (const float*)d_in[11];
  float* out = (float*)d_out;

  if (ws_size < WS_NEED) return;

  char* ws = (char*)d_ws;
  uint8_t*  P    = (uint8_t*) (ws + OFF_P);     // h0 u8; Y3 aliases (h0 dead after layer1)
  uint8_t*  Y3   = (uint8_t*) (ws + OFF_P);
  uint8_t*  Q    = (uint8_t*) (ws + OFF_Q);
  float*    tmpf = (float*)   (ws + OFF_TMP);
  uint32_t* zp   = (uint32_t*)(ws + OFF_ZP);
  uint8_t*  zp8  = (uint8_t*) (ws + OFF_ZP);
  uint16_t* Wt1  = (uint16_t*)(ws + OFF_WT1);
  uint16_t* Wt2  = (uint16_t*)(ws + OFF_WT2);
  uint16_t* Wt3  = (uint16_t*)(ws + OFF_WT3);
  float*    scP  = (float*)   (ws + OFF_SCP);
  float*    scQ  = (float*)   (ws + OFF_SCQ);
  float*    scY  = (float*)   (ws + OFF_SCY);
  int*      deg  = (int*)     (ws + OFF_DEG);
  int*      rp   = (int*)     (ws + OFF_RP);
  int*      cur  = (int*)     (ws + OFF_CUR);
  uint16_t* cols = (uint16_t*)(ws + OFF_COLS);

  k_zero_deg<<<(NT+255)/256, 256, 0, stream>>>(deg);
  k_count   <<<(NE+255)/256, 256, 0, stream>>>(ei, deg);
  k_scan    <<<1, 1024, 0, stream>>>(deg, rp, cur);
  k_init    <<<442, 256, 0, stream>>>(zp, (uint32_t*)cols, scP, scQ, scY);
  k_fill    <<<(NE+255)/256, 256, 0, stream>>>(ei, cur, cols);
  k_prepw   <<<1, 256, 0, stream>>>(W1, W2, W3, Wt1, Wt2, Wt3);

  for (int ch = 0; ch < 2; ch++){
    k_build_h0<<<NT/16, 256, 0, stream>>>(x + (size_t)ch*32*NT*14, tidx, emb, P, scP);
    k_layer1<<<NT/2, 256, 0, stream>>>(P, scP, Q, scQ, rp, cur, cols, zp8, Wt1, b1);
    k_l2g3  <<<NT/2, 256, 0, stream>>>(Q, scQ, Y3, scY, rp, cur, cols, zp8, Wt2, b2, Wt3);
    k_fin   <<<NT/2, 256, 0, stream>>>(Y3, scY, rp, cur, cols, zp8, b3, Wo, bo, tmpf);
    k_tr    <<<(NT+255)/256, 256, 0, stream>>>(tmpf, out + (size_t)ch*32*NT);
  }
}